// Round 6
// baseline (214.846 us; speedup 1.0000x reference)
//
#include <hip/hip_runtime.h>
#include <hip/hip_bf16.h>

// Deformable attention (Deformable-DETR) on MI355X.
// Static problem: B=8, NQ=900, E=256, H=8, L=4, P=4, dh=32, NV=19560
// levels (h,w): (92,160) (46,80) (23,40) (12,20); starts 0,14720,18400,19320

#define B_   8
#define NQ_  900
#define E_   256
#define H_   8
#define NV_  19560
#define M_TOT (B_ * NV_)   // 156480 = 64 * 2445 exactly
#define MQ_  (B_ * NQ_)    // 7200 = 32 * 225 exactly

typedef __attribute__((ext_vector_type(8)))  __bf16 bf16x8;
typedef __attribute__((ext_vector_type(4)))  float  f32x4;
typedef __attribute__((ext_vector_type(16))) float  f32x16;

__device__ __forceinline__ unsigned short f2bf(float x) {
    unsigned int u = __builtin_bit_cast(unsigned int, x);
    u += 0x7FFFu + ((u >> 16) & 1u);          // RNE to bf16
    return (unsigned short)(u >> 16);
}

__device__ __forceinline__ bf16x8 cvt8(f32x4 lo, f32x4 hi) {
    union { bf16x8 v; unsigned short u[8]; } r;
    r.u[0] = f2bf(lo.x); r.u[1] = f2bf(lo.y); r.u[2] = f2bf(lo.z); r.u[3] = f2bf(lo.w);
    r.u[4] = f2bf(hi.x); r.u[5] = f2bf(hi.y); r.u[6] = f2bf(hi.z); r.u[7] = f2bf(hi.w);
    return r.v;
}

#define GLL16(src, dst) \
    __builtin_amdgcn_global_load_lds( \
        (const __attribute__((address_space(1))) unsigned int*)(src), \
        (__attribute__((address_space(3))) unsigned int*)(dst), 16, 0, 0)

// ---------------------------------------------------------------- K0: prep
// Builds the three weight images in MFMA-B LDS layout:
//   img[((kf*2+h)*NCOL + col)*8 + j] = bf16( W[(kf*16 + h*8 + j)][col] )
// vimg: Wv (256 cols), oimg: Wo (256 cols), pimg: [Ws | Wa] (384 cols).
__global__ __launch_bounds__(256) void k_prep(
    const float* __restrict__ Wv, const float* __restrict__ Wo,
    const float* __restrict__ Ws, const float* __restrict__ Wa,
    unsigned short* __restrict__ vimg, unsigned short* __restrict__ oimg,
    unsigned short* __restrict__ pimg)
{
    const int i = blockIdx.x * 256 + threadIdx.x;   // 0..229375
    if (i < 131072) {
        const int e = i & 65535;
        const int j = e & 7, col = (e >> 3) & 255, h = (e >> 11) & 1, kf = e >> 12;
        const int k = kf * 16 + h * 8 + j;
        const float w = (i < 65536) ? Wv[k * 256 + col] : Wo[k * 256 + col];
        ((i < 65536) ? vimg : oimg)[e] = f2bf(w);
    } else {
        const int e = i - 131072;                   // 0..98303
        const int j = e & 7;
        const int q = e >> 3;                       // 0..12287
        const int col = q % 384, s = q / 384;
        const int h = s & 1, kf = s >> 1;
        const int k = kf * 16 + h * 8 + j;
        pimg[e] = f2bf(col < 256 ? Ws[k * 256 + col] : Wa[k * 128 + (col - 256)]);
    }
}

// ---------------------------------------------------------------- K1: params (MFMA)
// [off | attn-logits] = query @ [Ws|Wa] + [bs|ba]; softmax fused in epilogue.
// BM=32, N=384, 4 waves x 96 cols. Persistent-B: 96KB LDS, 2 K-phases.
__global__ __launch_bounds__(256) void k_params(
    const float* __restrict__ query, const unsigned short* __restrict__ pimg,
    const float* __restrict__ bs, const float* __restrict__ ba,
    float* __restrict__ off_out, float* __restrict__ attn_out)
{
    __shared__ unsigned short sB[49152];   // 96 KB: [kf8][h2][col384][8]
    const int t = threadIdx.x, w = t >> 6, l = t & 63;
    const int lr = l & 31, hh = l >> 5;
    const int row0 = blockIdx.x * 32;
    const float* arow = query + (long)(row0 + lr) * 256;

    f32x16 acc[3];
#pragma unroll
    for (int n = 0; n < 3; ++n) acc[n] = (f32x16)(0.f);

    f32x4 al[2], ah[2];
    al[0] = *(const f32x4*)(arow + 0 * 16 + hh * 8);
    ah[0] = *(const f32x4*)(arow + 0 * 16 + hh * 8 + 4);
    al[1] = *(const f32x4*)(arow + 1 * 16 + hh * 8);
    ah[1] = *(const f32x4*)(arow + 1 * 16 + hh * 8 + 4);

#pragma unroll
    for (int i = 0; i < 24; ++i)
        GLL16(pimg + (i * 256 + t) * 8, sB + (i * 256 + t) * 8);
    __syncthreads();

#pragma unroll
    for (int ph = 0; ph < 2; ++ph) {
        if (ph == 1) {
            __syncthreads();
#pragma unroll
            for (int i = 0; i < 24; ++i)
                GLL16(pimg + 49152 + (i * 256 + t) * 8, sB + (i * 256 + t) * 8);
            __syncthreads();
        }
#pragma unroll
        for (int kfp = 0; kfp < 8; ++kfp) {
            const int g = ph * 8 + kfp;
            const int s = g & 1;
            const bf16x8 a8 = cvt8(al[s], ah[s]);
            if (g + 2 < 16) {
                al[s] = *(const f32x4*)(arow + (g + 2) * 16 + hh * 8);
                ah[s] = *(const f32x4*)(arow + (g + 2) * 16 + hh * 8 + 4);
            }
#pragma unroll
            for (int n = 0; n < 3; ++n) {
                const bf16x8 b8 = *(const bf16x8*)
                    (sB + (((kfp * 2 + hh) * 384) + w * 96 + n * 32 + lr) * 8);
                acc[n] = __builtin_amdgcn_mfma_f32_32x32x16_bf16(a8, b8, acc[n], 0, 0, 0);
            }
        }
    }

    __syncthreads();                        // all MFMA reads of sB done
    float* slog = (float*)sB;               // reuse: [32 rows][128 attn cols]
#pragma unroll
    for (int n = 0; n < 3; ++n) {
        const int gcol = w * 96 + n * 32 + lr;
#pragma unroll
        for (int r = 0; r < 16; ++r) {
            const int rl = (r & 3) + 8 * (r >> 2) + 4 * hh;
            if (gcol < 256)
                off_out[(long)(row0 + rl) * 256 + gcol] = acc[n][r] + bs[gcol];
            else
                slog[rl * 128 + (gcol - 256)] = acc[n][r] + ba[gcol - 256];
        }
    }
    __syncthreads();
    {
        const int row = t >> 3, h = t & 7;
        const float* pl = slog + row * 128 + h * 16;
        float m = pl[0];
#pragma unroll
        for (int j = 1; j < 16; ++j) m = fmaxf(m, pl[j]);
        float e[16]; float ssum = 0.f;
#pragma unroll
        for (int j = 0; j < 16; ++j) { e[j] = expf(pl[j] - m); ssum += e[j]; }
        const float inv = 1.0f / ssum;
        float* po = attn_out + (long)(row0 + row) * 128 + h * 16;
#pragma unroll
        for (int j = 0; j < 16; ++j) po[j] = e[j] * inv;
    }
}

// ---------------------------------------------------------------- K2: v proj (MFMA)
// v = value @ Wv + bv, stored bf16. BM=64, N=256, 4 waves x 64 cols.
// Persistent-B (64KB, 2 K-phases, 3 barriers/block). A direct global->reg in
// fragment layout with sliding prefetch (no A-LDS, no per-step barriers).
// 32x32 C-frag -> full-64B-line bf16 stores (no write amplification).
__global__ __launch_bounds__(256) void k_vgemm(
    const float* __restrict__ value, const unsigned short* __restrict__ vimg,
    const float* __restrict__ bv, unsigned short* __restrict__ v_out)
{
    __shared__ unsigned short sB[32768];   // 64 KB: [kf8][h2][col256][8]
    const int t = threadIdx.x, w = t >> 6, l = t & 63;
    const int lr = l & 31, hh = l >> 5;
    const int row0 = blockIdx.x * 64;
    const float* arow0 = value + (long)(row0 + lr) * 256;
    const float* arow1 = value + (long)(row0 + 32 + lr) * 256;

    f32x16 acc[2][2];
#pragma unroll
    for (int m = 0; m < 2; ++m)
#pragma unroll
        for (int n = 0; n < 2; ++n) acc[m][n] = (f32x16)(0.f);

    f32x4 al[2][2], ah[2][2];  // [slot][m]
#pragma unroll
    for (int s = 0; s < 2; ++s) {
        al[s][0] = *(const f32x4*)(arow0 + s * 16 + hh * 8);
        ah[s][0] = *(const f32x4*)(arow0 + s * 16 + hh * 8 + 4);
        al[s][1] = *(const f32x4*)(arow1 + s * 16 + hh * 8);
        ah[s][1] = *(const f32x4*)(arow1 + s * 16 + hh * 8 + 4);
    }

#pragma unroll
    for (int i = 0; i < 16; ++i)
        GLL16(vimg + (i * 256 + t) * 8, sB + (i * 256 + t) * 8);
    __syncthreads();

#pragma unroll
    for (int ph = 0; ph < 2; ++ph) {
        if (ph == 1) {
            __syncthreads();
#pragma unroll
            for (int i = 0; i < 16; ++i)
                GLL16(vimg + 32768 + (i * 256 + t) * 8, sB + (i * 256 + t) * 8);
            __syncthreads();
        }
#pragma unroll
        for (int kfp = 0; kfp < 8; ++kfp) {
            const int g = ph * 8 + kfp;
            const int s = g & 1;
            bf16x8 a8[2];
            a8[0] = cvt8(al[s][0], ah[s][0]);
            a8[1] = cvt8(al[s][1], ah[s][1]);
            if (g + 2 < 16) {
                al[s][0] = *(const f32x4*)(arow0 + (g + 2) * 16 + hh * 8);
                ah[s][0] = *(const f32x4*)(arow0 + (g + 2) * 16 + hh * 8 + 4);
                al[s][1] = *(const f32x4*)(arow1 + (g + 2) * 16 + hh * 8);
                ah[s][1] = *(const f32x4*)(arow1 + (g + 2) * 16 + hh * 8 + 4);
            }
            bf16x8 b8[2];
#pragma unroll
            for (int n = 0; n < 2; ++n)
                b8[n] = *(const bf16x8*)
                    (sB + (((kfp * 2 + hh) * 256) + w * 64 + n * 32 + lr) * 8);
#pragma unroll
            for (int m = 0; m < 2; ++m)
#pragma unroll
                for (int n = 0; n < 2; ++n)
                    acc[m][n] = __builtin_amdgcn_mfma_f32_32x32x16_bf16(
                        a8[m], b8[n], acc[m][n], 0, 0, 0);
        }
    }

    // epilogue: full-line bf16 stores (32 lanes x 2B contiguous per row-half)
#pragma unroll
    for (int n = 0; n < 2; ++n) {
        const int col = w * 64 + n * 32 + lr;
        const float bb = bv[col];
#pragma unroll
        for (int m = 0; m < 2; ++m)
#pragma unroll
            for (int r = 0; r < 16; ++r) {
                const int row = row0 + m * 32 + (r & 3) + 8 * (r >> 2) + 4 * hh;
                v_out[(long)row * 256 + col] = f2bf(acc[m][n][r] + bb);
            }
    }
}

// ---------------------------------------------------------------- K3: sample
// One block per (b,q); 256 threads = 8 heads x 32 dh. mid stored bf16.
__global__ __launch_bounds__(256) void k_sample(
    const float* __restrict__ refp, const float* __restrict__ off,
    const float* __restrict__ attn, const __hip_bfloat16* __restrict__ v,
    unsigned short* __restrict__ out_mid)
{
    __shared__ float soff[256];
    __shared__ float satt[128];
    __shared__ float sref[8];
    const int t = threadIdx.x;
    const int bq = blockIdx.x;
    const int b = bq / NQ_;
    soff[t] = off[bq * 256 + t];
    if (t < 128) satt[t] = attn[bq * 128 + t];
    if (t < 8)   sref[t] = refp[bq * 8 + t];
    __syncthreads();

    const int h = t >> 5, d = t & 31;
    const __hip_bfloat16* vb = v + (long)b * NV_ * 256 + h * 32 + d;
    float acc = 0.f;

    constexpr int HS[4] = {92, 46, 23, 12};
    constexpr int WS_[4] = {160, 80, 40, 20};
    constexpr int ST[4] = {0, 14720, 18400, 19320};
#pragma unroll
    for (int l = 0; l < 4; ++l) {
        const int Hl = HS[l], Wl = WS_[l], st = ST[l];
        const float rx = sref[l * 2 + 0], ry = sref[l * 2 + 1];
#pragma unroll
        for (int p = 0; p < 4; ++p) {
            const int c = h * 32 + l * 8 + p * 2;
            const float x = fmaf(rx, (float)Wl, soff[c])     - 0.5f;
            const float y = fmaf(ry, (float)Hl, soff[c + 1]) - 0.5f;
            const float aw = satt[h * 16 + l * 4 + p];
            const float x0f = floorf(x), y0f = floorf(y);
            const int x0 = (int)x0f, y0 = (int)y0f;
            const float wx1 = x - x0f, wx0 = 1.f - wx1;
            const float wy1 = y - y0f, wy0 = 1.f - wy1;
            const bool vx0 = (x0 >= 0) && (x0 < Wl);
            const bool vx1 = (x0 + 1 >= 0) && (x0 + 1 < Wl);
            if (y0 >= 0 && y0 < Hl) {
                const __hip_bfloat16* rowp = vb + (long)(st + y0 * Wl) * 256;
                if (vx0) acc += __bfloat162float(rowp[(long)x0 * 256])       * (wx0 * wy0 * aw);
                if (vx1) acc += __bfloat162float(rowp[(long)(x0 + 1) * 256]) * (wx1 * wy0 * aw);
            }
            if (y0 + 1 >= 0 && y0 + 1 < Hl) {
                const __hip_bfloat16* rowp = vb + (long)(st + (y0 + 1) * Wl) * 256;
                if (vx0) acc += __bfloat162float(rowp[(long)x0 * 256])       * (wx0 * wy1 * aw);
                if (vx1) acc += __bfloat162float(rowp[(long)(x0 + 1) * 256]) * (wx1 * wy1 * aw);
            }
        }
    }
    out_mid[bq * 256 + t] = f2bf(acc);
}

// ---------------------------------------------------------------- K4: out GEMM (MFMA)
// out = mid(bf16) @ Wo + bo + query. BM=32, persistent-B 64KB, 2 phases.
__global__ __launch_bounds__(256) void k_ogemm(
    const unsigned short* __restrict__ mid, const unsigned short* __restrict__ oimg,
    const float* __restrict__ bo, const float* __restrict__ query,
    float* __restrict__ out)
{
    __shared__ unsigned short sB[32768];   // 64 KB
    const int t = threadIdx.x, w = t >> 6, l = t & 63;
    const int lr = l & 31, hh = l >> 5;
    const int row0 = blockIdx.x * 32;
    const unsigned short* arow = mid + (long)(row0 + lr) * 256;

    f32x16 acc[2];
#pragma unroll
    for (int n = 0; n < 2; ++n) acc[n] = (f32x16)(0.f);

    bf16x8 areg[2];
    areg[0] = *(const bf16x8*)(arow + 0 * 16 + hh * 8);
    areg[1] = *(const bf16x8*)(arow + 1 * 16 + hh * 8);

#pragma unroll
    for (int i = 0; i < 16; ++i)
        GLL16(oimg + (i * 256 + t) * 8, sB + (i * 256 + t) * 8);
    __syncthreads();

#pragma unroll
    for (int ph = 0; ph < 2; ++ph) {
        if (ph == 1) {
            __syncthreads();
#pragma unroll
            for (int i = 0; i < 16; ++i)
                GLL16(oimg + 32768 + (i * 256 + t) * 8, sB + (i * 256 + t) * 8);
            __syncthreads();
        }
#pragma unroll
        for (int kfp = 0; kfp < 8; ++kfp) {
            const int g = ph * 8 + kfp;
            const int s = g & 1;
            const bf16x8 a8 = areg[s];
            if (g + 2 < 16)
                areg[s] = *(const bf16x8*)(arow + (g + 2) * 16 + hh * 8);
#pragma unroll
            for (int n = 0; n < 2; ++n) {
                const bf16x8 b8 = *(const bf16x8*)
                    (sB + (((kfp * 2 + hh) * 256) + w * 64 + n * 32 + lr) * 8);
                acc[n] = __builtin_amdgcn_mfma_f32_32x32x16_bf16(a8, b8, acc[n], 0, 0, 0);
            }
        }
    }

#pragma unroll
    for (int n = 0; n < 2; ++n) {
        const int col = w * 64 + n * 32 + lr;
        const float bb = bo[col];
#pragma unroll
        for (int r = 0; r < 16; ++r) {
            const int row = row0 + (r & 3) + 8 * (r >> 2) + 4 * hh;
            out[(long)row * 256 + col] = acc[n][r] + bb + query[(long)row * 256 + col];
        }
    }
}

// ---------------------------------------------------------------- launch
extern "C" void kernel_launch(void* const* d_in, const int* in_sizes, int n_in,
                              void* d_out, int out_size, void* d_ws, size_t ws_size,
                              hipStream_t stream)
{
    const float* query = (const float*)d_in[0];
    const float* value = (const float*)d_in[1];
    const float* refp  = (const float*)d_in[2];
    const float* Wv    = (const float*)d_in[3];
    const float* bv    = (const float*)d_in[4];
    const float* Ws    = (const float*)d_in[5];
    const float* bs    = (const float*)d_in[6];
    const float* Wa    = (const float*)d_in[7];
    const float* ba    = (const float*)d_in[8];
    const float* Wo    = (const float*)d_in[9];
    const float* bo    = (const float*)d_in[10];
    float* out = (float*)d_out;

    char* ws = (char*)d_ws;
    unsigned short* v_ws  = (unsigned short*)ws;                    // 80,117,760 B
    float* off_ws  = (float*)(ws + 80117760);                       //  7,372,800 B
    float* attn_ws = (float*)(ws + 87490560);                       //  3,686,400 B
    unsigned short* mid_ws  = (unsigned short*)(ws + 91176960);     //  3,686,400 B
    unsigned short* vimg_ws = (unsigned short*)(ws + 94863360);     //    131,072 B
    unsigned short* pimg_ws = (unsigned short*)(ws + 94994432);     //    196,608 B
    unsigned short* oimg_ws = (unsigned short*)(ws + 95191040);     //    131,072 B

    k_prep  <<<dim3(896), dim3(256), 0, stream>>>(Wv, Wo, Ws, Wa, vimg_ws, oimg_ws, pimg_ws);
    k_params<<<dim3(MQ_ / 32), dim3(256), 0, stream>>>(query, pimg_ws, bs, ba, off_ws, attn_ws);
    k_vgemm <<<dim3(M_TOT / 64), dim3(256), 0, stream>>>(value, vimg_ws, bv, v_ws);
    k_sample<<<dim3(MQ_), dim3(256), 0, stream>>>(refp, off_ws, attn_ws,
                                                  (const __hip_bfloat16*)v_ws, mid_ws);
    k_ogemm <<<dim3(MQ_ / 32), dim3(256), 0, stream>>>(mid_ws, oimg_ws, bo, query, out);
}

// Round 7
// 170.065 us; speedup vs baseline: 1.2633x; 1.2633x over previous
//
#include <hip/hip_runtime.h>
#include <hip/hip_bf16.h>

// Deformable attention (Deformable-DETR) on MI355X.
// Static problem: B=8, NQ=900, E=256, H=8, L=4, P=4, dh=32, NV=19560
// levels (h,w): (92,160) (46,80) (23,40) (12,20); starts 0,14720,18400,19320

#define B_   8
#define NQ_  900
#define E_   256
#define H_   8
#define NV_  19560
#define M_TOT (B_ * NV_)   // 156480 = 64 * 2445 exactly
#define MQ_  (B_ * NQ_)    // 7200 = 32 * 225 exactly

typedef __attribute__((ext_vector_type(8)))  __bf16 bf16x8;
typedef __attribute__((ext_vector_type(4)))  float  f32x4;
typedef __attribute__((ext_vector_type(16))) float  f32x16;

__device__ __forceinline__ unsigned short f2bf(float x) {
    unsigned int u = __builtin_bit_cast(unsigned int, x);
    u += 0x7FFFu + ((u >> 16) & 1u);          // RNE to bf16
    return (unsigned short)(u >> 16);
}

__device__ __forceinline__ bf16x8 cvt8(f32x4 lo, f32x4 hi) {
    union { bf16x8 v; unsigned short u[8]; } r;
    r.u[0] = f2bf(lo.x); r.u[1] = f2bf(lo.y); r.u[2] = f2bf(lo.z); r.u[3] = f2bf(lo.w);
    r.u[4] = f2bf(hi.x); r.u[5] = f2bf(hi.y); r.u[6] = f2bf(hi.z); r.u[7] = f2bf(hi.w);
    return r.v;
}

#define GLL16(src, dst) \
    __builtin_amdgcn_global_load_lds( \
        (const __attribute__((address_space(1))) unsigned int*)(src), \
        (__attribute__((address_space(3))) unsigned int*)(dst), 16, 0, 0)

// ---------------------------------------------------------------- K0: prep
// Weight images in MFMA-B layout: img[(s*NCOL + col)*8 + j] = bf16(W[8s+j][col])
// (s = K16-step*2 + half). vimg: Wv, oimg: Wo (256 cols), pimg: [Ws|Wa] (384).
__global__ __launch_bounds__(256) void k_prep(
    const float* __restrict__ Wv, const float* __restrict__ Wo,
    const float* __restrict__ Ws, const float* __restrict__ Wa,
    unsigned short* __restrict__ vimg, unsigned short* __restrict__ oimg,
    unsigned short* __restrict__ pimg)
{
    const int i = blockIdx.x * 256 + threadIdx.x;   // 0..229375
    if (i < 131072) {
        const int e = i & 65535;
        const int j = e & 7, col = (e >> 3) & 255, h = (e >> 11) & 1, kf = e >> 12;
        const int k = kf * 16 + h * 8 + j;
        const float w = (i < 65536) ? Wv[k * 256 + col] : Wo[k * 256 + col];
        ((i < 65536) ? vimg : oimg)[e] = f2bf(w);
    } else {
        const int e = i - 131072;                   // 0..98303
        const int j = e & 7;
        const int q = e >> 3;                       // 0..12287
        const int col = q % 384, s = q / 384;
        const int h = s & 1, kf = s >> 1;
        const int k = kf * 16 + h * 8 + j;
        pimg[e] = f2bf(col < 256 ? Ws[k * 256 + col] : Wa[k * 128 + (col - 256)]);
    }
}

// ---------------------------------------------------------------- K1: params (MFMA)
// [off | attn-logits] = query @ [Ws|Wa] + [bs|ba]; softmax fused in epilogue.
__global__ __launch_bounds__(256) void k_params(
    const float* __restrict__ query, const unsigned short* __restrict__ pimg,
    const float* __restrict__ bs, const float* __restrict__ ba,
    float* __restrict__ off_out, float* __restrict__ attn_out)
{
    __shared__ unsigned short sB[49152];   // 96 KB: [kf8][h2][col384][8]
    const int t = threadIdx.x, w = t >> 6, l = t & 63;
    const int lr = l & 31, hh = l >> 5;
    const int row0 = blockIdx.x * 32;
    const float* arow = query + (long)(row0 + lr) * 256;

    f32x16 acc[3];
#pragma unroll
    for (int n = 0; n < 3; ++n) acc[n] = (f32x16)(0.f);

    f32x4 al[2], ah[2];
    al[0] = *(const f32x4*)(arow + 0 * 16 + hh * 8);
    ah[0] = *(const f32x4*)(arow + 0 * 16 + hh * 8 + 4);
    al[1] = *(const f32x4*)(arow + 1 * 16 + hh * 8);
    ah[1] = *(const f32x4*)(arow + 1 * 16 + hh * 8 + 4);

#pragma unroll
    for (int i = 0; i < 24; ++i)
        GLL16(pimg + (i * 256 + t) * 8, sB + (i * 256 + t) * 8);
    __syncthreads();

#pragma unroll
    for (int ph = 0; ph < 2; ++ph) {
        if (ph == 1) {
            __syncthreads();
#pragma unroll
            for (int i = 0; i < 24; ++i)
                GLL16(pimg + 49152 + (i * 256 + t) * 8, sB + (i * 256 + t) * 8);
            __syncthreads();
        }
#pragma unroll
        for (int kfp = 0; kfp < 8; ++kfp) {
            const int g = ph * 8 + kfp;
            const int s = g & 1;
            const bf16x8 a8 = cvt8(al[s], ah[s]);
            if (g + 2 < 16) {
                al[s] = *(const f32x4*)(arow + (g + 2) * 16 + hh * 8);
                ah[s] = *(const f32x4*)(arow + (g + 2) * 16 + hh * 8 + 4);
            }
#pragma unroll
            for (int n = 0; n < 3; ++n) {
                const bf16x8 b8 = *(const bf16x8*)
                    (sB + (((kfp * 2 + hh) * 384) + w * 96 + n * 32 + lr) * 8);
                acc[n] = __builtin_amdgcn_mfma_f32_32x32x16_bf16(a8, b8, acc[n], 0, 0, 0);
            }
        }
    }

    __syncthreads();                        // all MFMA reads of sB done
    float* slog = (float*)sB;               // reuse: [32 rows][128 attn cols]
#pragma unroll
    for (int n = 0; n < 3; ++n) {
        const int gcol = w * 96 + n * 32 + lr;
#pragma unroll
        for (int r = 0; r < 16; ++r) {
            const int rl = (r & 3) + 8 * (r >> 2) + 4 * hh;
            if (gcol < 256)
                off_out[(long)(row0 + rl) * 256 + gcol] = acc[n][r] + bs[gcol];
            else
                slog[rl * 128 + (gcol - 256)] = acc[n][r] + ba[gcol - 256];
        }
    }
    __syncthreads();
    {
        const int row = t >> 3, h = t & 7;
        const float* pl = slog + row * 128 + h * 16;
        float m = pl[0];
#pragma unroll
        for (int j = 1; j < 16; ++j) m = fmaxf(m, pl[j]);
        float e[16]; float ssum = 0.f;
#pragma unroll
        for (int j = 0; j < 16; ++j) { e[j] = expf(pl[j] - m); ssum += e[j]; }
        const float inv = 1.0f / ssum;
        float* po = attn_out + (long)(row0 + row) * 128 + h * 16;
#pragma unroll
        for (int j = 0; j < 16; ++j) po[j] = e[j] * inv;
    }
}

// ---------------------------------------------------------------- K2: v proj (MFMA)
// v = value @ Wv + bv, stored bf16. BM=64, BN=256, BK=32 x 8 tiles.
// 3-deep counted-vmcnt pipeline (T4): both A(fp32) and B(bf16 image) staged
// via global_load_lds; vmcnt never drained to 0 mid-loop; raw s_barrier.
// A's XOR unit-swizzle encoded in the per-lane GLOBAL source address (m173).
__device__ __forceinline__ void vg_stage(
    const float* __restrict__ value, const unsigned short* __restrict__ vimg,
    unsigned short* sA, unsigned short* sB, int row0, int ks, int t)
{
#pragma unroll
    for (int i = 0; i < 2; ++i) {               // A: 64 rows x 32 K fp32 (8 KB)
        const int u = i * 256 + t;              // 16B unit index
        const int row = u >> 3, qs = u & 7;
        const float* src = value + (long)(row0 + row) * 256 + ks * 32
                           + ((qs ^ (row & 7)) << 2);
        GLL16(src, sA + u * 8);
    }
#pragma unroll
    for (int i = 0; i < 4; ++i) {               // B: 256 cols x 32 K bf16 (16 KB)
        const int u = i * 256 + t;
        GLL16(vimg + (ks * 1024 + u) * 8, sB + u * 8);
    }
}

__device__ __forceinline__ void vg_compute(
    const unsigned short* sA, const unsigned short* sB,
    int lr, int hh, int w, f32x16 acc[2][2])
{
#pragma unroll
    for (int kk = 0; kk < 2; ++kk) {
        bf16x8 a8[2], b8[2];
#pragma unroll
        for (int m = 0; m < 2; ++m) {
            const int row = m * 32 + lr;
            const int q0 = kk * 4 + hh * 2;
            const f32x4 lo = *(const f32x4*)(sA + (row * 8 + ((q0    ) ^ (row & 7))) * 8);
            const f32x4 hi = *(const f32x4*)(sA + (row * 8 + ((q0 + 1) ^ (row & 7))) * 8);
            a8[m] = cvt8(lo, hi);
        }
#pragma unroll
        for (int n = 0; n < 2; ++n)
            b8[n] = *(const bf16x8*)(sB + ((kk * 2 + hh) * 256 + w * 64 + n * 32 + lr) * 8);
#pragma unroll
        for (int m = 0; m < 2; ++m)
#pragma unroll
            for (int n = 0; n < 2; ++n)
                acc[m][n] = __builtin_amdgcn_mfma_f32_32x32x16_bf16(
                    a8[m], b8[n], acc[m][n], 0, 0, 0);
    }
}

__global__ __launch_bounds__(256) void k_vgemm(
    const float* __restrict__ value, const unsigned short* __restrict__ vimg,
    const float* __restrict__ bv, unsigned short* __restrict__ v_out)
{
    __shared__ __attribute__((aligned(16))) unsigned short sm[36864];  // 72 KB
    unsigned short* const sA_ = sm;           // 3 x 4096 ushorts (8 KB each)
    unsigned short* const sB_ = sm + 12288;   // 3 x 8192 ushorts (16 KB each)
#define SA_(p) (sA_ + (p) * 4096)
#define SB_(p) (sB_ + (p) * 8192)

    const int t = threadIdx.x, w = t >> 6, l = t & 63;
    const int lr = l & 31, hh = l >> 5;
    const int row0 = blockIdx.x * 64;

    f32x16 acc[2][2];
#pragma unroll
    for (int m = 0; m < 2; ++m)
#pragma unroll
        for (int n = 0; n < 2; ++n) acc[m][n] = (f32x16)(0.f);

    // prologue: 2 tiles in flight (12 instr/wave)
    vg_stage(value, vimg, SA_(0), SB_(0), row0, 0, t);
    vg_stage(value, vimg, SA_(1), SB_(1), row0, 1, t);

#pragma unroll
    for (int ks = 0; ks < 8; ++ks) {
        if (ks < 6)
            vg_stage(value, vimg, SA_((ks + 2) % 3), SB_((ks + 2) % 3), row0, ks + 2, t);
        // wait ONLY for tile ks (6 instr/tile/wave); keep the rest in flight
        if (ks < 6)      asm volatile("s_waitcnt vmcnt(12)" ::: "memory");
        else if (ks == 6) asm volatile("s_waitcnt vmcnt(6)" ::: "memory");
        else             asm volatile("s_waitcnt vmcnt(0)" ::: "memory");
        __builtin_amdgcn_sched_barrier(0);
        __builtin_amdgcn_s_barrier();
        vg_compute(SA_(ks % 3), SB_(ks % 3), lr, hh, w, acc);
        __builtin_amdgcn_s_barrier();
        __builtin_amdgcn_sched_barrier(0);
    }

    // epilogue: full-line bf16 stores (32 lanes x 2B contiguous)
#pragma unroll
    for (int n = 0; n < 2; ++n) {
        const int col = w * 64 + n * 32 + lr;
        const float bb = bv[col];
#pragma unroll
        for (int m = 0; m < 2; ++m)
#pragma unroll
            for (int r = 0; r < 16; ++r) {
                const int row = row0 + m * 32 + (r & 3) + 8 * (r >> 2) + 4 * hh;
                v_out[(long)row * 256 + col] = f2bf(acc[m][n][r] + bb);
            }
    }
}

// ---------------------------------------------------------------- K3: sample
// One block per (b,q); 256 threads = 8 heads x 32 dh. mid stored bf16.
__global__ __launch_bounds__(256) void k_sample(
    const float* __restrict__ refp, const float* __restrict__ off,
    const float* __restrict__ attn, const __hip_bfloat16* __restrict__ v,
    unsigned short* __restrict__ out_mid)
{
    __shared__ float soff[256];
    __shared__ float satt[128];
    __shared__ float sref[8];
    const int t = threadIdx.x;
    const int bq = blockIdx.x;
    const int b = bq / NQ_;
    soff[t] = off[bq * 256 + t];
    if (t < 128) satt[t] = attn[bq * 128 + t];
    if (t < 8)   sref[t] = refp[bq * 8 + t];
    __syncthreads();

    const int h = t >> 5, d = t & 31;
    const __hip_bfloat16* vb = v + (long)b * NV_ * 256 + h * 32 + d;
    float acc = 0.f;

    constexpr int HS[4] = {92, 46, 23, 12};
    constexpr int WS_[4] = {160, 80, 40, 20};
    constexpr int ST[4] = {0, 14720, 18400, 19320};
#pragma unroll
    for (int l = 0; l < 4; ++l) {
        const int Hl = HS[l], Wl = WS_[l], st = ST[l];
        const float rx = sref[l * 2 + 0], ry = sref[l * 2 + 1];
#pragma unroll
        for (int p = 0; p < 4; ++p) {
            const int c = h * 32 + l * 8 + p * 2;
            const float x = fmaf(rx, (float)Wl, soff[c])     - 0.5f;
            const float y = fmaf(ry, (float)Hl, soff[c + 1]) - 0.5f;
            const float aw = satt[h * 16 + l * 4 + p];
            const float x0f = floorf(x), y0f = floorf(y);
            const int x0 = (int)x0f, y0 = (int)y0f;
            const float wx1 = x - x0f, wx0 = 1.f - wx1;
            const float wy1 = y - y0f, wy0 = 1.f - wy1;
            const bool vx0 = (x0 >= 0) && (x0 < Wl);
            const bool vx1 = (x0 + 1 >= 0) && (x0 + 1 < Wl);
            if (y0 >= 0 && y0 < Hl) {
                const __hip_bfloat16* rowp = vb + (long)(st + y0 * Wl) * 256;
                if (vx0) acc += __bfloat162float(rowp[(long)x0 * 256])       * (wx0 * wy0 * aw);
                if (vx1) acc += __bfloat162float(rowp[(long)(x0 + 1) * 256]) * (wx1 * wy0 * aw);
            }
            if (y0 + 1 >= 0 && y0 + 1 < Hl) {
                const __hip_bfloat16* rowp = vb + (long)(st + (y0 + 1) * Wl) * 256;
                if (vx0) acc += __bfloat162float(rowp[(long)x0 * 256])       * (wx0 * wy1 * aw);
                if (vx1) acc += __bfloat162float(rowp[(long)(x0 + 1) * 256]) * (wx1 * wy1 * aw);
            }
        }
    }
    out_mid[bq * 256 + t] = f2bf(acc);
}

// ---------------------------------------------------------------- K4: out GEMM (MFMA)
// out = mid(bf16) @ Wo + bo + query. BM=32, persistent-B 64KB, 2 phases.
__global__ __launch_bounds__(256) void k_ogemm(
    const unsigned short* __restrict__ mid, const unsigned short* __restrict__ oimg,
    const float* __restrict__ bo, const float* __restrict__ query,
    float* __restrict__ out)
{
    __shared__ unsigned short sB[32768];   // 64 KB
    const int t = threadIdx.x, w = t >> 6, l = t & 63;
    const int lr = l & 31, hh = l >> 5;
    const int row0 = blockIdx.x * 32;
    const unsigned short* arow = mid + (long)(row0 + lr) * 256;

    f32x16 acc[2];
#pragma unroll
    for (int n = 0; n < 2; ++n) acc[n] = (f32x16)(0.f);

    bf16x8 areg[2];
    areg[0] = *(const bf16x8*)(arow + 0 * 16 + hh * 8);
    areg[1] = *(const bf16x8*)(arow + 1 * 16 + hh * 8);

#pragma unroll
    for (int i = 0; i < 16; ++i)
        GLL16(oimg + (i * 256 + t) * 8, sB + (i * 256 + t) * 8);
    __syncthreads();

#pragma unroll
    for (int ph = 0; ph < 2; ++ph) {
        if (ph == 1) {
            __syncthreads();
#pragma unroll
            for (int i = 0; i < 16; ++i)
                GLL16(oimg + 32768 + (i * 256 + t) * 8, sB + (i * 256 + t) * 8);
            __syncthreads();
        }
#pragma unroll
        for (int kfp = 0; kfp < 8; ++kfp) {
            const int g = ph * 8 + kfp;
            const int s = g & 1;
            const bf16x8 a8 = areg[s];
            if (g + 2 < 16)
                areg[s] = *(const bf16x8*)(arow + (g + 2) * 16 + hh * 8);
#pragma unroll
            for (int n = 0; n < 2; ++n) {
                const bf16x8 b8 = *(const bf16x8*)
                    (sB + (((kfp * 2 + hh) * 256) + w * 64 + n * 32 + lr) * 8);
                acc[n] = __builtin_amdgcn_mfma_f32_32x32x16_bf16(a8, b8, acc[n], 0, 0, 0);
            }
        }
    }

#pragma unroll
    for (int n = 0; n < 2; ++n) {
        const int col = w * 64 + n * 32 + lr;
        const float bb = bo[col];
#pragma unroll
        for (int r = 0; r < 16; ++r) {
            const int row = row0 + (r & 3) + 8 * (r >> 2) + 4 * hh;
            out[(long)row * 256 + col] = acc[n][r] + bb + query[(long)row * 256 + col];
        }
    }
}

// ---------------------------------------------------------------- launch
extern "C" void kernel_launch(void* const* d_in, const int* in_sizes, int n_in,
                              void* d_out, int out_size, void* d_ws, size_t ws_size,
                              hipStream_t stream)
{
    const float* query = (const float*)d_in[0];
    const float* value = (const float*)d_in[1];
    const float* refp  = (const float*)d_in[2];
    const float* Wv    = (const float*)d_in[3];
    const float* bv    = (const float*)d_in[4];
    const float* Ws    = (const float*)d_in[5];
    const float* bs    = (const float*)d_in[6];
    const float* Wa    = (const float*)d_in[7];
    const float* ba    = (const float*)d_in[8];
    const float* Wo    = (const float*)d_in[9];
    const float* bo    = (const float*)d_in[10];
    float* out = (float*)d_out;

    char* ws = (char*)d_ws;
    unsigned short* v_ws  = (unsigned short*)ws;                    // 80,117,760 B
    float* off_ws  = (float*)(ws + 80117760);                       //  7,372,800 B
    float* attn_ws = (float*)(ws + 87490560);                       //  3,686,400 B
    unsigned short* mid_ws  = (unsigned short*)(ws + 91176960);     //  3,686,400 B
    unsigned short* vimg_ws = (unsigned short*)(ws + 94863360);     //    131,072 B
    unsigned short* pimg_ws = (unsigned short*)(ws + 94994432);     //    196,608 B
    unsigned short* oimg_ws = (unsigned short*)(ws + 95191040);     //    131,072 B

    k_prep  <<<dim3(896), dim3(256), 0, stream>>>(Wv, Wo, Ws, Wa, vimg_ws, oimg_ws, pimg_ws);
    k_params<<<dim3(MQ_ / 32), dim3(256), 0, stream>>>(query, pimg_ws, bs, ba, off_ws, attn_ws);
    k_vgemm <<<dim3(M_TOT / 64), dim3(256), 0, stream>>>(value, vimg_ws, bv, v_ws);
    k_sample<<<dim3(MQ_), dim3(256), 0, stream>>>(refp, off_ws, attn_ws,
                                                  (const __hip_bfloat16*)v_ws, mid_ws);
    k_ogemm <<<dim3(MQ_ / 32), dim3(256), 0, stream>>>(mid_ws, oimg_ws, bo, query, out);
}

// Round 9
// 132.025 us; speedup vs baseline: 1.6273x; 1.2881x over previous
//
#include <hip/hip_runtime.h>
#include <hip/hip_bf16.h>

// Deformable attention (Deformable-DETR) on MI355X.
// Static problem: B=8, NQ=900, E=256, H=8, L=4, P=4, dh=32, NV=19560
// levels (h,w): (92,160) (46,80) (23,40) (12,20); starts 0,14720,18400,19320

#define B_   8
#define NQ_  900
#define E_   256
#define H_   8
#define NV_  19560
#define M_TOT (B_ * NV_)   // 156480 = 64 * 2445 exactly
#define MQ_  (B_ * NQ_)    // 7200 = 32 * 225 exactly

typedef __attribute__((ext_vector_type(8)))  __bf16 bf16x8;
typedef __attribute__((ext_vector_type(4)))  float  f32x4;
typedef __attribute__((ext_vector_type(16))) float  f32x16;

__device__ __forceinline__ unsigned short f2bf(float x) {   // cold paths only
    unsigned int u = __builtin_bit_cast(unsigned int, x);
    u += 0x7FFFu + ((u >> 16) & 1u);          // RNE to bf16
    return (unsigned short)(u >> 16);
}

// hot-path conversion: v_cvt_pk_bf16_f32 via HIP intrinsic (1 op / 2 floats)
__device__ __forceinline__ unsigned int pack2bf(float a, float b) {
    union { __hip_bfloat162 h; unsigned int u; } r;
    r.h = __float22bfloat162_rn(make_float2(a, b));
    return r.u;
}

__device__ __forceinline__ bf16x8 cvt8(f32x4 lo, f32x4 hi) {
    union { bf16x8 v; unsigned int u[4]; } r;
    r.u[0] = pack2bf(lo.x, lo.y);
    r.u[1] = pack2bf(lo.z, lo.w);
    r.u[2] = pack2bf(hi.x, hi.y);
    r.u[3] = pack2bf(hi.z, hi.w);
    return r.v;
}

__device__ __forceinline__ unsigned short bf1(float x) {
    union { __hip_bfloat16 h; unsigned short u; } r;
    r.h = __float2bfloat16(x);
    return r.u;
}

#define GLL16(src, dst) \
    __builtin_amdgcn_global_load_lds( \
        (const __attribute__((address_space(1))) unsigned int*)(src), \
        (__attribute__((address_space(3))) unsigned int*)(dst), 16, 0, 0)

// ---------------------------------------------------------------- K0: prep
// Weight images in MFMA-B layout: img[(s*NCOL + col)*8 + j] = bf16(W[8s+j][col])
__global__ __launch_bounds__(256) void k_prep(
    const float* __restrict__ Wv, const float* __restrict__ Wo,
    const float* __restrict__ Ws, const float* __restrict__ Wa,
    unsigned short* __restrict__ vimg, unsigned short* __restrict__ oimg,
    unsigned short* __restrict__ pimg)
{
    const int i = blockIdx.x * 256 + threadIdx.x;   // 0..229375
    if (i < 131072) {
        const int e = i & 65535;
        const int j = e & 7, col = (e >> 3) & 255, h = (e >> 11) & 1, kf = e >> 12;
        const int k = kf * 16 + h * 8 + j;
        const float w = (i < 65536) ? Wv[k * 256 + col] : Wo[k * 256 + col];
        ((i < 65536) ? vimg : oimg)[e] = f2bf(w);
    } else {
        const int e = i - 131072;                   // 0..98303
        const int j = e & 7;
        const int q = e >> 3;                       // 0..12287
        const int col = q % 384, s = q / 384;
        const int h = s & 1, kf = s >> 1;
        const int k = kf * 16 + h * 8 + j;
        pimg[e] = f2bf(col < 256 ? Ws[k * 256 + col] : Wa[k * 128 + (col - 256)]);
    }
}

// ---------------------------------------------------------------- K1: params (MFMA)
// [off | attn-logits] = query @ [Ws|Wa] + [bs|ba]; softmax fused in epilogue.
__global__ __launch_bounds__(256) void k_params(
    const float* __restrict__ query, const unsigned short* __restrict__ pimg,
    const float* __restrict__ bs, const float* __restrict__ ba,
    float* __restrict__ off_out, float* __restrict__ attn_out)
{
    __shared__ unsigned short sB[49152];   // 96 KB: [kf8][h2][col384][8]
    const int t = threadIdx.x, w = t >> 6, l = t & 63;
    const int lr = l & 31, hh = l >> 5;
    const int row0 = blockIdx.x * 32;
    const float* arow = query + (long)(row0 + lr) * 256;

    f32x16 acc[3];
#pragma unroll
    for (int n = 0; n < 3; ++n) acc[n] = (f32x16)(0.f);

    f32x4 al[2], ah[2];
    al[0] = *(const f32x4*)(arow + 0 * 16 + hh * 8);
    ah[0] = *(const f32x4*)(arow + 0 * 16 + hh * 8 + 4);
    al[1] = *(const f32x4*)(arow + 1 * 16 + hh * 8);
    ah[1] = *(const f32x4*)(arow + 1 * 16 + hh * 8 + 4);

#pragma unroll
    for (int i = 0; i < 24; ++i)
        GLL16(pimg + (i * 256 + t) * 8, sB + (i * 256 + t) * 8);
    __syncthreads();

#pragma unroll
    for (int ph = 0; ph < 2; ++ph) {
        if (ph == 1) {
            __syncthreads();
#pragma unroll
            for (int i = 0; i < 24; ++i)
                GLL16(pimg + 49152 + (i * 256 + t) * 8, sB + (i * 256 + t) * 8);
            __syncthreads();
        }
#pragma unroll
        for (int kfp = 0; kfp < 8; ++kfp) {
            const int g = ph * 8 + kfp;
            const int s = g & 1;
            const bf16x8 a8 = cvt8(al[s], ah[s]);
            if (g + 2 < 16) {
                al[s] = *(const f32x4*)(arow + (g + 2) * 16 + hh * 8);
                ah[s] = *(const f32x4*)(arow + (g + 2) * 16 + hh * 8 + 4);
            }
#pragma unroll
            for (int n = 0; n < 3; ++n) {
                const bf16x8 b8 = *(const bf16x8*)
                    (sB + (((kfp * 2 + hh) * 384) + w * 96 + n * 32 + lr) * 8);
                acc[n] = __builtin_amdgcn_mfma_f32_32x32x16_bf16(a8, b8, acc[n], 0, 0, 0);
            }
        }
    }

    __syncthreads();                        // all MFMA reads of sB done
    float* slog = (float*)sB;               // reuse: [32 rows][128 attn cols]
#pragma unroll
    for (int n = 0; n < 3; ++n) {
        const int gcol = w * 96 + n * 32 + lr;
#pragma unroll
        for (int r = 0; r < 16; ++r) {
            const int rl = (r & 3) + 8 * (r >> 2) + 4 * hh;
            if (gcol < 256)
                off_out[(long)(row0 + rl) * 256 + gcol] = acc[n][r] + bs[gcol];
            else
                slog[rl * 128 + (gcol - 256)] = acc[n][r] + ba[gcol - 256];
        }
    }
    __syncthreads();
    {
        const int row = t >> 3, h = t & 7;
        const float* pl = slog + row * 128 + h * 16;
        float m = pl[0];
#pragma unroll
        for (int j = 1; j < 16; ++j) m = fmaxf(m, pl[j]);
        float e[16]; float ssum = 0.f;
#pragma unroll
        for (int j = 0; j < 16; ++j) { e[j] = expf(pl[j] - m); ssum += e[j]; }
        const float inv = 1.0f / ssum;
        float* po = attn_out + (long)(row0 + row) * 128 + h * 16;
#pragma unroll
        for (int j = 0; j < 16; ++j) po[j] = e[j] * inv;
    }
}

// ---------------------------------------------------------------- K2: v proj (MFMA)
// v = value @ Wv + bv, stored bf16. BM=64, BN=256, BK=32 x 8 tiles.
// 3-deep counted-vmcnt pipeline; pk-cvt A conversion; setprio on MFMA.
__device__ __forceinline__ void vg_stage(
    const float* __restrict__ value, const unsigned short* __restrict__ vimg,
    unsigned short* sA, unsigned short* sB, int row0, int ks, int t)
{
#pragma unroll
    for (int i = 0; i < 2; ++i) {               // A: 64 rows x 32 K fp32 (8 KB)
        const int u = i * 256 + t;              // 16B unit index
        const int row = u >> 3, qs = u & 7;
        const float* src = value + (long)(row0 + row) * 256 + ks * 32
                           + ((qs ^ (row & 7)) << 2);
        GLL16(src, sA + u * 8);
    }
#pragma unroll
    for (int i = 0; i < 4; ++i) {               // B: 256 cols x 32 K bf16 (16 KB)
        const int u = i * 256 + t;
        GLL16(vimg + (ks * 1024 + u) * 8, sB + u * 8);
    }
}

__device__ __forceinline__ void vg_compute(
    const unsigned short* sA, const unsigned short* sB,
    int lr, int hh, int w, f32x16 acc[2][2])
{
#pragma unroll
    for (int kk = 0; kk < 2; ++kk) {
        bf16x8 a8[2], b8[2];
#pragma unroll
        for (int m = 0; m < 2; ++m) {
            const int row = m * 32 + lr;
            const int q0 = kk * 4 + hh * 2;
            const f32x4 lo = *(const f32x4*)(sA + (row * 8 + ((q0    ) ^ (row & 7))) * 8);
            const f32x4 hi = *(const f32x4*)(sA + (row * 8 + ((q0 + 1) ^ (row & 7))) * 8);
            a8[m] = cvt8(lo, hi);
        }
#pragma unroll
        for (int n = 0; n < 2; ++n)
            b8[n] = *(const bf16x8*)(sB + ((kk * 2 + hh) * 256 + w * 64 + n * 32 + lr) * 8);
        __builtin_amdgcn_s_setprio(1);
#pragma unroll
        for (int m = 0; m < 2; ++m)
#pragma unroll
            for (int n = 0; n < 2; ++n)
                acc[m][n] = __builtin_amdgcn_mfma_f32_32x32x16_bf16(
                    a8[m], b8[n], acc[m][n], 0, 0, 0);
        __builtin_amdgcn_s_setprio(0);
    }
}

__global__ __launch_bounds__(256) void k_vgemm(
    const float* __restrict__ value, const unsigned short* __restrict__ vimg,
    const float* __restrict__ bv, unsigned short* __restrict__ v_out)
{
    __shared__ __attribute__((aligned(16))) unsigned short sm[36864];  // 72 KB
    unsigned short* const sA_ = sm;           // 3 x 4096 ushorts (8 KB each)
    unsigned short* const sB_ = sm + 12288;   // 3 x 8192 ushorts (16 KB each)
#define SA_(p) (sA_ + (p) * 4096)
#define SB_(p) (sB_ + (p) * 8192)

    const int t = threadIdx.x, w = t >> 6, l = t & 63;
    const int lr = l & 31, hh = l >> 5;
    const int row0 = blockIdx.x * 64;

    f32x16 acc[2][2];
#pragma unroll
    for (int m = 0; m < 2; ++m)
#pragma unroll
        for (int n = 0; n < 2; ++n) acc[m][n] = (f32x16)(0.f);

    // prologue: 2 tiles in flight (12 instr/wave)
    vg_stage(value, vimg, SA_(0), SB_(0), row0, 0, t);
    vg_stage(value, vimg, SA_(1), SB_(1), row0, 1, t);

#pragma unroll
    for (int ks = 0; ks < 8; ++ks) {
        if (ks < 6)
            vg_stage(value, vimg, SA_((ks + 2) % 3), SB_((ks + 2) % 3), row0, ks + 2, t);
        // wait ONLY for tile ks (6 instr/tile/wave); keep the rest in flight
        if (ks < 6)      asm volatile("s_waitcnt vmcnt(12)" ::: "memory");
        else if (ks == 6) asm volatile("s_waitcnt vmcnt(6)" ::: "memory");
        else             asm volatile("s_waitcnt vmcnt(0)" ::: "memory");
        __builtin_amdgcn_sched_barrier(0);
        __builtin_amdgcn_s_barrier();
        vg_compute(SA_(ks % 3), SB_(ks % 3), lr, hh, w, acc);
        __builtin_amdgcn_s_barrier();
        __builtin_amdgcn_sched_barrier(0);
    }

    // epilogue: full-line bf16 stores (32 lanes x 2B contiguous)
#pragma unroll
    for (int n = 0; n < 2; ++n) {
        const int col = w * 64 + n * 32 + lr;
        const float bb = bv[col];
#pragma unroll
        for (int m = 0; m < 2; ++m)
#pragma unroll
            for (int r = 0; r < 16; ++r) {
                const int row = row0 + m * 32 + (r & 3) + 8 * (r >> 2) + 4 * hh;
                v_out[(long)row * 256 + col] = bf1(acc[m][n][r] + bb);
            }
    }
}

// ---------------------------------------------------------------- K3: sample
// 2 queries/block; per query 128 threads = 8 heads x 16 dh-pairs.
// Each lane loads a dh-PAIR as one uint (2 bf16) -> VMEM instrs halve.
__global__ __launch_bounds__(256) void k_sample(
    const float* __restrict__ refp, const float* __restrict__ off,
    const float* __restrict__ attn, const unsigned short* __restrict__ v,
    unsigned short* __restrict__ out_mid)
{
    __shared__ float soff[512];
    __shared__ float satt[256];
    __shared__ float sref[16];
    const int t = threadIdx.x;
    if (t < 128) ((float4*)soff)[t] = ((const float4*)(off + (long)blockIdx.x * 512))[t];
    if (t < 64)  ((float4*)satt)[t] = ((const float4*)(attn + (long)blockIdx.x * 256))[t];
    if (t < 4)   ((float4*)sref)[t] = ((const float4*)(refp + (long)blockIdx.x * 16))[t];
    __syncthreads();

    const int qi = t >> 7, tt = t & 127;
    const int h = tt >> 4, dp = tt & 15;          // head, dh-pair
    const int bq = blockIdx.x * 2 + qi;
    const int b = bq / NQ_;
    // uint view of v: row stride = 128 uints; this lane's col pair:
    const unsigned int* vb = (const unsigned int*)(v + (long)b * NV_ * 256)
                             + h * 16 + dp;
    float acc0 = 0.f, acc1 = 0.f;

    constexpr int HS[4] = {92, 46, 23, 12};
    constexpr int WS_[4] = {160, 80, 40, 20};
    constexpr int ST[4] = {0, 14720, 18400, 19320};
#pragma unroll
    for (int l = 0; l < 4; ++l) {
        const int Hl = HS[l], Wl = WS_[l], st = ST[l];
        const float rx = sref[qi * 8 + l * 2 + 0], ry = sref[qi * 8 + l * 2 + 1];
#pragma unroll
        for (int p = 0; p < 4; ++p) {
            const int c = h * 32 + l * 8 + p * 2;
            const float x = fmaf(rx, (float)Wl, soff[qi * 256 + c])     - 0.5f;
            const float y = fmaf(ry, (float)Hl, soff[qi * 256 + c + 1]) - 0.5f;
            const float aw = satt[qi * 128 + h * 16 + l * 4 + p];
            const float x0f = floorf(x), y0f = floorf(y);
            const int x0 = (int)x0f, y0 = (int)y0f;
            const float wx1 = x - x0f, wx0 = 1.f - wx1;
            const float wy1 = y - y0f, wy0 = 1.f - wy1;
            const bool vx0 = (x0 >= 0) && (x0 < Wl);
            const bool vx1 = (x0 + 1 >= 0) && (x0 + 1 < Wl);
#pragma unroll
            for (int dy = 0; dy < 2; ++dy) {
                const int yy = y0 + dy;
                if (yy >= 0 && yy < Hl) {
                    const float wy = dy ? wy1 : wy0;
                    const unsigned int* rowp = vb + (long)(st + yy * Wl) * 128;
                    if (vx0) {
                        const unsigned int u = rowp[(long)x0 * 128];
                        const float f0 = __builtin_bit_cast(float, u << 16);
                        const float f1 = __builtin_bit_cast(float, u & 0xFFFF0000u);
                        const float wgt = wx0 * wy * aw;
                        acc0 = fmaf(f0, wgt, acc0);
                        acc1 = fmaf(f1, wgt, acc1);
                    }
                    if (vx1) {
                        const unsigned int u = rowp[(long)(x0 + 1) * 128];
                        const float f0 = __builtin_bit_cast(float, u << 16);
                        const float f1 = __builtin_bit_cast(float, u & 0xFFFF0000u);
                        const float wgt = wx1 * wy * aw;
                        acc0 = fmaf(f0, wgt, acc0);
                        acc1 = fmaf(f1, wgt, acc1);
                    }
                }
            }
        }
    }
    *(unsigned int*)(out_mid + (long)bq * 256 + h * 32 + dp * 2) = pack2bf(acc0, acc1);
}

// ---------------------------------------------------------------- K4: out GEMM (MFMA)
// out = mid(bf16) @ Wo + bo + query. BM=32, persistent-B 64KB, 2 phases.
__global__ __launch_bounds__(256) void k_ogemm(
    const unsigned short* __restrict__ mid, const unsigned short* __restrict__ oimg,
    const float* __restrict__ bo, const float* __restrict__ query,
    float* __restrict__ out)
{
    __shared__ unsigned short sB[32768];   // 64 KB
    const int t = threadIdx.x, w = t >> 6, l = t & 63;
    const int lr = l & 31, hh = l >> 5;
    const int row0 = blockIdx.x * 32;
    const unsigned short* arow = mid + (long)(row0 + lr) * 256;

    f32x16 acc[2];
#pragma unroll
    for (int n = 0; n < 2; ++n) acc[n] = (f32x16)(0.f);

    bf16x8 areg[2];
    areg[0] = *(const bf16x8*)(arow + 0 * 16 + hh * 8);
    areg[1] = *(const bf16x8*)(arow + 1 * 16 + hh * 8);

#pragma unroll
    for (int i = 0; i < 16; ++i)
        GLL16(oimg + (i * 256 + t) * 8, sB + (i * 256 + t) * 8);
    __syncthreads();

#pragma unroll
    for (int ph = 0; ph < 2; ++ph) {
        if (ph == 1) {
            __syncthreads();
#pragma unroll
            for (int i = 0; i < 16; ++i)
                GLL16(oimg + 32768 + (i * 256 + t) * 8, sB + (i * 256 + t) * 8);
            __syncthreads();
        }
#pragma unroll
        for (int kfp = 0; kfp < 8; ++kfp) {
            const int g = ph * 8 + kfp;
            const int s = g & 1;
            const bf16x8 a8 = areg[s];
            if (g + 2 < 16)
                areg[s] = *(const bf16x8*)(arow + (g + 2) * 16 + hh * 8);
#pragma unroll
            for (int n = 0; n < 2; ++n) {
                const bf16x8 b8 = *(const bf16x8*)
                    (sB + (((kfp * 2 + hh) * 256) + w * 64 + n * 32 + lr) * 8);
                acc[n] = __builtin_amdgcn_mfma_f32_32x32x16_bf16(a8, b8, acc[n], 0, 0, 0);
            }
        }
    }

#pragma unroll
    for (int n = 0; n < 2; ++n) {
        const int col = w * 64 + n * 32 + lr;
        const float bb = bo[col];
#pragma unroll
        for (int r = 0; r < 16; ++r) {
            const int row = row0 + (r & 3) + 8 * (r >> 2) + 4 * hh;
            out[(long)row * 256 + col] = acc[n][r] + bb + query[(long)row * 256 + col];
        }
    }
}

// ---------------------------------------------------------------- launch
extern "C" void kernel_launch(void* const* d_in, const int* in_sizes, int n_in,
                              void* d_out, int out_size, void* d_ws, size_t ws_size,
                              hipStream_t stream)
{
    const float* query = (const float*)d_in[0];
    const float* value = (const float*)d_in[1];
    const float* refp  = (const float*)d_in[2];
    const float* Wv    = (const float*)d_in[3];
    const float* bv    = (const float*)d_in[4];
    const float* Ws    = (const float*)d_in[5];
    const float* bs    = (const float*)d_in[6];
    const float* Wa    = (const float*)d_in[7];
    const float* ba    = (const float*)d_in[8];
    const float* Wo    = (const float*)d_in[9];
    const float* bo    = (const float*)d_in[10];
    float* out = (float*)d_out;

    char* ws = (char*)d_ws;
    unsigned short* v_ws  = (unsigned short*)ws;                    // 80,117,760 B
    float* off_ws  = (float*)(ws + 80117760);                       //  7,372,800 B
    float* attn_ws = (float*)(ws + 87490560);                       //  3,686,400 B
    unsigned short* mid_ws  = (unsigned short*)(ws + 91176960);     //  3,686,400 B
    unsigned short* vimg_ws = (unsigned short*)(ws + 94863360);     //    131,072 B
    unsigned short* pimg_ws = (unsigned short*)(ws + 94994432);     //    196,608 B
    unsigned short* oimg_ws = (unsigned short*)(ws + 95191040);     //    131,072 B

    k_prep  <<<dim3(896), dim3(256), 0, stream>>>(Wv, Wo, Ws, Wa, vimg_ws, oimg_ws, pimg_ws);
    k_params<<<dim3(MQ_ / 32), dim3(256), 0, stream>>>(query, pimg_ws, bs, ba, off_ws, attn_ws);
    k_vgemm <<<dim3(M_TOT / 64), dim3(256), 0, stream>>>(value, vimg_ws, bv, v_ws);
    k_sample<<<dim3(MQ_ / 2), dim3(256), 0, stream>>>(refp, off_ws, attn_ws, v_ws, mid_ws);
    k_ogemm <<<dim3(MQ_ / 32), dim3(256), 0, stream>>>(mid_ws, oimg_ws, bo, query, out);
}

// Round 10
// 102.241 us; speedup vs baseline: 2.1014x; 1.2913x over previous
//
#include <hip/hip_runtime.h>
#include <hip/hip_bf16.h>

// Deformable attention (Deformable-DETR) on MI355X.
// Static problem: B=8, NQ=900, E=256, H=8, L=4, P=4, dh=32, NV=19560
// levels (h,w): (92,160) (46,80) (23,40) (12,20); starts 0,14720,18400,19320

#define B_   8
#define NQ_  900
#define E_   256
#define H_   8
#define NV_  19560
#define M_TOT (B_ * NV_)   // 156480 = 64 * 2445 exactly
#define MQ_  (B_ * NQ_)    // 7200 = 32 * 225 exactly

typedef __attribute__((ext_vector_type(8)))  __bf16 bf16x8;
typedef __attribute__((ext_vector_type(4)))  float  f32x4;
typedef __attribute__((ext_vector_type(16))) float  f32x16;

__device__ __forceinline__ unsigned short f2bf(float x) {   // cold paths only
    unsigned int u = __builtin_bit_cast(unsigned int, x);
    u += 0x7FFFu + ((u >> 16) & 1u);          // RNE to bf16
    return (unsigned short)(u >> 16);
}

// hot-path conversion: v_cvt_pk_bf16_f32 via HIP intrinsic (1 op / 2 floats)
__device__ __forceinline__ unsigned int pack2bf(float a, float b) {
    union { __hip_bfloat162 h; unsigned int u; } r;
    r.h = __float22bfloat162_rn(make_float2(a, b));
    return r.u;
}

__device__ __forceinline__ bf16x8 cvt8(f32x4 lo, f32x4 hi) {
    union { bf16x8 v; unsigned int u[4]; } r;
    r.u[0] = pack2bf(lo.x, lo.y);
    r.u[1] = pack2bf(lo.z, lo.w);
    r.u[2] = pack2bf(hi.x, hi.y);
    r.u[3] = pack2bf(hi.z, hi.w);
    return r.v;
}

__device__ __forceinline__ unsigned short bf1(float x) {
    union { __hip_bfloat16 h; unsigned short u; } r;
    r.h = __float2bfloat16(x);
    return r.u;
}

#define GLL16(src, dst) \
    __builtin_amdgcn_global_load_lds( \
        (const __attribute__((address_space(1))) unsigned int*)(src), \
        (__attribute__((address_space(3))) unsigned int*)(dst), 16, 0, 0)

// ---------------------------------------------------------------- K0: prep
// Weight images in MFMA-B layout: img[(s*NCOL + col)*8 + j] = bf16(W[8s+j][col])
__global__ __launch_bounds__(256) void k_prep(
    const float* __restrict__ Wv, const float* __restrict__ Wo,
    const float* __restrict__ Ws, const float* __restrict__ Wa,
    unsigned short* __restrict__ vimg, unsigned short* __restrict__ oimg,
    unsigned short* __restrict__ pimg)
{
    const int i = blockIdx.x * 256 + threadIdx.x;   // 0..229375
    if (i < 131072) {
        const int e = i & 65535;
        const int j = e & 7, col = (e >> 3) & 255, h = (e >> 11) & 1, kf = e >> 12;
        const int k = kf * 16 + h * 8 + j;
        const float w = (i < 65536) ? Wv[k * 256 + col] : Wo[k * 256 + col];
        ((i < 65536) ? vimg : oimg)[e] = f2bf(w);
    } else {
        const int e = i - 131072;                   // 0..98303
        const int j = e & 7;
        const int q = e >> 3;                       // 0..12287
        const int col = q % 384, s = q / 384;
        const int h = s & 1, kf = s >> 1;
        const int k = kf * 16 + h * 8 + j;
        pimg[e] = f2bf(col < 256 ? Ws[k * 256 + col] : Wa[k * 128 + (col - 256)]);
    }
}

// ---------------------------------------------------------------- K1: params (MFMA)
// [off | attn-logits] = query @ [Ws|Wa] + [bs|ba]; softmax fused in epilogue.
__global__ __launch_bounds__(256) void k_params(
    const float* __restrict__ query, const unsigned short* __restrict__ pimg,
    const float* __restrict__ bs, const float* __restrict__ ba,
    float* __restrict__ off_out, float* __restrict__ attn_out)
{
    __shared__ unsigned short sB[49152];   // 96 KB: [kf8][h2][col384][8]
    const int t = threadIdx.x, w = t >> 6, l = t & 63;
    const int lr = l & 31, hh = l >> 5;
    const int row0 = blockIdx.x * 32;
    const float* arow = query + (long)(row0 + lr) * 256;

    f32x16 acc[3];
#pragma unroll
    for (int n = 0; n < 3; ++n) acc[n] = (f32x16)(0.f);

    f32x4 al[2], ah[2];
    al[0] = *(const f32x4*)(arow + 0 * 16 + hh * 8);
    ah[0] = *(const f32x4*)(arow + 0 * 16 + hh * 8 + 4);
    al[1] = *(const f32x4*)(arow + 1 * 16 + hh * 8);
    ah[1] = *(const f32x4*)(arow + 1 * 16 + hh * 8 + 4);

#pragma unroll
    for (int i = 0; i < 24; ++i)
        GLL16(pimg + (i * 256 + t) * 8, sB + (i * 256 + t) * 8);
    __syncthreads();

#pragma unroll
    for (int ph = 0; ph < 2; ++ph) {
        if (ph == 1) {
            __syncthreads();
#pragma unroll
            for (int i = 0; i < 24; ++i)
                GLL16(pimg + 49152 + (i * 256 + t) * 8, sB + (i * 256 + t) * 8);
            __syncthreads();
        }
#pragma unroll
        for (int kfp = 0; kfp < 8; ++kfp) {
            const int g = ph * 8 + kfp;
            const int s = g & 1;
            const bf16x8 a8 = cvt8(al[s], ah[s]);
            if (g + 2 < 16) {
                al[s] = *(const f32x4*)(arow + (g + 2) * 16 + hh * 8);
                ah[s] = *(const f32x4*)(arow + (g + 2) * 16 + hh * 8 + 4);
            }
#pragma unroll
            for (int n = 0; n < 3; ++n) {
                const bf16x8 b8 = *(const bf16x8*)
                    (sB + (((kfp * 2 + hh) * 384) + w * 96 + n * 32 + lr) * 8);
                acc[n] = __builtin_amdgcn_mfma_f32_32x32x16_bf16(a8, b8, acc[n], 0, 0, 0);
            }
        }
    }

    __syncthreads();                        // all MFMA reads of sB done
    float* slog = (float*)sB;               // reuse: [32 rows][128 attn cols]
#pragma unroll
    for (int n = 0; n < 3; ++n) {
        const int gcol = w * 96 + n * 32 + lr;
#pragma unroll
        for (int r = 0; r < 16; ++r) {
            const int rl = (r & 3) + 8 * (r >> 2) + 4 * hh;
            if (gcol < 256)
                off_out[(long)(row0 + rl) * 256 + gcol] = acc[n][r] + bs[gcol];
            else
                slog[rl * 128 + (gcol - 256)] = acc[n][r] + ba[gcol - 256];
        }
    }
    __syncthreads();
    {
        const int row = t >> 3, h = t & 7;
        const float* pl = slog + row * 128 + h * 16;
        float m = pl[0];
#pragma unroll
        for (int j = 1; j < 16; ++j) m = fmaxf(m, pl[j]);
        float e[16]; float ssum = 0.f;
#pragma unroll
        for (int j = 0; j < 16; ++j) { e[j] = expf(pl[j] - m); ssum += e[j]; }
        const float inv = 1.0f / ssum;
        float* po = attn_out + (long)(row0 + row) * 128 + h * 16;
#pragma unroll
        for (int j = 0; j < 16; ++j) po[j] = e[j] * inv;
    }
}

// ---------------------------------------------------------------- K2: v proj (MFMA)
// v = value @ Wv + bv, stored bf16. BM=64, BN=256, BK=32 x 8 tiles.
// 2-buffer counted-vmcnt pipeline, 48KB LDS -> 3 blocks/CU (3 independent
// barrier domains per CU). Stage-after-compute into the just-freed buffer.
__device__ __forceinline__ void vg_stage(
    const float* __restrict__ value, const unsigned short* __restrict__ vimg,
    unsigned short* sA, unsigned short* sB, int row0, int ks, int t)
{
#pragma unroll
    for (int i = 0; i < 2; ++i) {               // A: 64 rows x 32 K fp32 (8 KB)
        const int u = i * 256 + t;              // 16B unit index
        const int row = u >> 3, qs = u & 7;
        const float* src = value + (long)(row0 + row) * 256 + ks * 32
                           + ((qs ^ (row & 7)) << 2);
        GLL16(src, sA + u * 8);
    }
#pragma unroll
    for (int i = 0; i < 4; ++i) {               // B: 256 cols x 32 K bf16 (16 KB)
        const int u = i * 256 + t;
        GLL16(vimg + (ks * 1024 + u) * 8, sB + u * 8);
    }
}

__device__ __forceinline__ void vg_compute(
    const unsigned short* sA, const unsigned short* sB,
    int lr, int hh, int w, f32x16 acc[2][2])
{
#pragma unroll
    for (int kk = 0; kk < 2; ++kk) {
        bf16x8 a8[2], b8[2];
#pragma unroll
        for (int m = 0; m < 2; ++m) {
            const int row = m * 32 + lr;
            const int q0 = kk * 4 + hh * 2;
            const f32x4 lo = *(const f32x4*)(sA + (row * 8 + ((q0    ) ^ (row & 7))) * 8);
            const f32x4 hi = *(const f32x4*)(sA + (row * 8 + ((q0 + 1) ^ (row & 7))) * 8);
            a8[m] = cvt8(lo, hi);
        }
#pragma unroll
        for (int n = 0; n < 2; ++n)
            b8[n] = *(const bf16x8*)(sB + ((kk * 2 + hh) * 256 + w * 64 + n * 32 + lr) * 8);
        __builtin_amdgcn_s_setprio(1);
#pragma unroll
        for (int m = 0; m < 2; ++m)
#pragma unroll
            for (int n = 0; n < 2; ++n)
                acc[m][n] = __builtin_amdgcn_mfma_f32_32x32x16_bf16(
                    a8[m], b8[n], acc[m][n], 0, 0, 0);
        __builtin_amdgcn_s_setprio(0);
    }
}

__global__ __launch_bounds__(256) void k_vgemm(
    const float* __restrict__ value, const unsigned short* __restrict__ vimg,
    const float* __restrict__ bv, unsigned short* __restrict__ v_out)
{
    __shared__ __attribute__((aligned(16))) unsigned short sm[24576];  // 48 KB
    unsigned short* const sA_ = sm;           // 2 x 4096 ushorts (8 KB each)
    unsigned short* const sB_ = sm + 8192;    // 2 x 8192 ushorts (16 KB each)
#define SA_(p) (sA_ + (p) * 4096)
#define SB_(p) (sB_ + (p) * 8192)

    const int t = threadIdx.x, w = t >> 6, l = t & 63;
    const int lr = l & 31, hh = l >> 5;
    const int row0 = blockIdx.x * 64;

    f32x16 acc[2][2];
#pragma unroll
    for (int m = 0; m < 2; ++m)
#pragma unroll
        for (int n = 0; n < 2; ++n) acc[m][n] = (f32x16)(0.f);

    // prologue: 2 tiles in flight (12 instr/wave)
    vg_stage(value, vimg, SA_(0), SB_(0), row0, 0, t);
    vg_stage(value, vimg, SA_(1), SB_(1), row0, 1, t);

#pragma unroll
    for (int ks = 0; ks < 8; ++ks) {
        // wait ONLY for tile ks (6 instr/tile/wave); keep tile ks+1 in flight
        if (ks < 7) asm volatile("s_waitcnt vmcnt(6)" ::: "memory");
        else        asm volatile("s_waitcnt vmcnt(0)" ::: "memory");
        __builtin_amdgcn_sched_barrier(0);
        __builtin_amdgcn_s_barrier();
        vg_compute(SA_(ks & 1), SB_(ks & 1), lr, hh, w, acc);
        __builtin_amdgcn_s_barrier();
        __builtin_amdgcn_sched_barrier(0);
        if (ks < 6)   // stage tile ks+2 into the buffer tile ks just vacated
            vg_stage(value, vimg, SA_(ks & 1), SB_(ks & 1), row0, ks + 2, t);
    }

    // epilogue: full-line bf16 stores (32 lanes x 2B contiguous)
#pragma unroll
    for (int n = 0; n < 2; ++n) {
        const int col = w * 64 + n * 32 + lr;
        const float bb = bv[col];
#pragma unroll
        for (int m = 0; m < 2; ++m)
#pragma unroll
            for (int r = 0; r < 16; ++r) {
                const int row = row0 + m * 32 + (r & 3) + 8 * (r >> 2) + 4 * hh;
                v_out[(long)row * 256 + col] = bf1(acc[m][n][r] + bb);
            }
    }
}

// ---------------------------------------------------------------- K3: sample
// Two-phase: phase 1 computes each point's 4 {offset, weight} pairs ONCE
// (256 threads = 256 points = 2 queries x 128); phase 2 is pure table-driven
// gather: 16 dh-pair lanes per head read the same LDS entry (broadcast).
__global__ __launch_bounds__(256) void k_sample(
    const float* __restrict__ refp, const float* __restrict__ off,
    const float* __restrict__ attn, const unsigned short* __restrict__ v,
    unsigned short* __restrict__ out_mid)
{
    __shared__ int2 spt[1024];   // [point(256)][corner(4)] = {elem-offset, weight bits}
    const int t = threadIdx.x;
    const int bq0 = blockIdx.x * 2;

    constexpr int HS[4] = {92, 46, 23, 12};
    constexpr int WS_[4] = {160, 80, 40, 20};
    constexpr int ST[4] = {0, 14720, 18400, 19320};

    // ---- phase 1: one point per thread ----
    {
        const int qi = t >> 7, c = t & 127;
        const int h = c >> 4, lv = (c >> 2) & 3, p = c & 3;
        const int bq = bq0 + qi;
        const int Hl = HS[lv], Wl = WS_[lv], st = ST[lv];
        const float rx = refp[bq * 8 + lv * 2 + 0];
        const float ry = refp[bq * 8 + lv * 2 + 1];
        const float ox = off[(long)bq * 256 + h * 32 + lv * 8 + p * 2 + 0];
        const float oy = off[(long)bq * 256 + h * 32 + lv * 8 + p * 2 + 1];
        const float aw = attn[(long)bq * 128 + h * 16 + lv * 4 + p];
        const float x = fmaf(rx, (float)Wl, ox) - 0.5f;
        const float y = fmaf(ry, (float)Hl, oy) - 0.5f;
        const float x0f = floorf(x), y0f = floorf(y);
        const int x0 = (int)x0f, y0 = (int)y0f;
        const float wx1 = x - x0f, wx0 = 1.f - wx1;
        const float wy1 = y - y0f, wy0 = 1.f - wy1;
#pragma unroll
        for (int cnr = 0; cnr < 4; ++cnr) {
            const int dx = cnr & 1, dy = cnr >> 1;
            const int xi = x0 + dx, yi = y0 + dy;
            const bool valid = (xi >= 0) && (xi < Wl) && (yi >= 0) && (yi < Hl);
            const int xc = min(max(xi, 0), Wl - 1);
            const int yc = min(max(yi, 0), Hl - 1);
            const float wgt = (dx ? wx1 : wx0) * (dy ? wy1 : wy0) * aw;
            spt[t * 4 + cnr] = make_int2((st + yc * Wl + xc) * 128,
                                         __builtin_bit_cast(int, valid ? wgt : 0.f));
        }
    }
    __syncthreads();

    // ---- phase 2: table-driven gather ----
    const int qi = t >> 7, tt = t & 127;
    const int h = tt >> 4, dp = tt & 15;
    const int bq = bq0 + qi;
    const int b = bq / NQ_;
    const unsigned int* vb = (const unsigned int*)(v + (long)b * NV_ * 256)
                             + h * 16 + dp;
    const int2* tbl = spt + (qi * 128 + h * 16) * 4;
    float acc0 = 0.f, acc1 = 0.f;
#pragma unroll
    for (int j = 0; j < 16; ++j) {
#pragma unroll
        for (int cnr = 0; cnr < 4; ++cnr) {
            const int2 ow = tbl[j * 4 + cnr];
            const unsigned int u = vb[ow.x];
            const float wgt = __builtin_bit_cast(float, ow.y);
            acc0 = fmaf(__builtin_bit_cast(float, u << 16), wgt, acc0);
            acc1 = fmaf(__builtin_bit_cast(float, u & 0xFFFF0000u), wgt, acc1);
        }
    }
    *(unsigned int*)(out_mid + (long)bq * 256 + h * 32 + dp * 2) = pack2bf(acc0, acc1);
}

// ---------------------------------------------------------------- K4: out GEMM (MFMA)
// out = mid(bf16) @ Wo + bo + query. BM=32, persistent-B 64KB, 2 phases.
__global__ __launch_bounds__(256) void k_ogemm(
    const unsigned short* __restrict__ mid, const unsigned short* __restrict__ oimg,
    const float* __restrict__ bo, const float* __restrict__ query,
    float* __restrict__ out)
{
    __shared__ unsigned short sB[32768];   // 64 KB
    const int t = threadIdx.x, w = t >> 6, l = t & 63;
    const int lr = l & 31, hh = l >> 5;
    const int row0 = blockIdx.x * 32;
    const unsigned short* arow = mid + (long)(row0 + lr) * 256;

    f32x16 acc[2];
#pragma unroll
    for (int n = 0; n < 2; ++n) acc[n] = (f32x16)(0.f);

    bf16x8 areg[2];
    areg[0] = *(const bf16x8*)(arow + 0 * 16 + hh * 8);
    areg[1] = *(const bf16x8*)(arow + 1 * 16 + hh * 8);

#pragma unroll
    for (int i = 0; i < 16; ++i)
        GLL16(oimg + (i * 256 + t) * 8, sB + (i * 256 + t) * 8);
    __syncthreads();

#pragma unroll
    for (int ph = 0; ph < 2; ++ph) {
        if (ph == 1) {
            __syncthreads();
#pragma unroll
            for (int i = 0; i < 16; ++i)
                GLL16(oimg + 32768 + (i * 256 + t) * 8, sB + (i * 256 + t) * 8);
            __syncthreads();
        }
#pragma unroll
        for (int kfp = 0; kfp < 8; ++kfp) {
            const int g = ph * 8 + kfp;
            const int s = g & 1;
            const bf16x8 a8 = areg[s];
            if (g + 2 < 16)
                areg[s] = *(const bf16x8*)(arow + (g + 2) * 16 + hh * 8);
#pragma unroll
            for (int n = 0; n < 2; ++n) {
                const bf16x8 b8 = *(const bf16x8*)
                    (sB + (((kfp * 2 + hh) * 256) + w * 64 + n * 32 + lr) * 8);
                acc[n] = __builtin_amdgcn_mfma_f32_32x32x16_bf16(a8, b8, acc[n], 0, 0, 0);
            }
        }
    }

#pragma unroll
    for (int n = 0; n < 2; ++n) {
        const int col = w * 64 + n * 32 + lr;
        const float bb = bo[col];
#pragma unroll
        for (int r = 0; r < 16; ++r) {
            const int row = row0 + (r & 3) + 8 * (r >> 2) + 4 * hh;
            out[(long)row * 256 + col] = acc[n][r] + bb + query[(long)row * 256 + col];
        }
    }
}

// ---------------------------------------------------------------- launch
extern "C" void kernel_launch(void* const* d_in, const int* in_sizes, int n_in,
                              void* d_out, int out_size, void* d_ws, size_t ws_size,
                              hipStream_t stream)
{
    const float* query = (const float*)d_in[0];
    const float* value = (const float*)d_in[1];
    const float* refp  = (const float*)d_in[2];
    const float* Wv    = (const float*)d_in[3];
    const float* bv    = (const float*)d_in[4];
    const float* Ws    = (const float*)d_in[5];
    const float* bs    = (const float*)d_in[6];
    const float* Wa    = (const float*)d_in[7];
    const float* ba    = (const float*)d_in[8];
    const float* Wo    = (const float*)d_in[9];
    const float* bo    = (const float*)d_in[10];
    float* out = (float*)d_out;

    char* ws = (char*)d_ws;
    unsigned short* v_ws  = (unsigned short*)ws;                    // 80,117,760 B
    float* off_ws  = (float*)(ws + 80117760);                       //  7,372,800 B
    float* attn_ws = (float*)(ws + 87490560);                       //  3,686,400 B
    unsigned short* mid_ws  = (unsigned short*)(ws + 91176960);     //  3,686,400 B
    unsigned short* vimg_ws = (unsigned short*)(ws + 94863360);     //    131,072 B
    unsigned short* pimg_ws = (unsigned short*)(ws + 94994432);     //    196,608 B
    unsigned short* oimg_ws = (unsigned short*)(ws + 95191040);     //    131,072 B

    k_prep  <<<dim3(896), dim3(256), 0, stream>>>(Wv, Wo, Ws, Wa, vimg_ws, oimg_ws, pimg_ws);
    k_params<<<dim3(MQ_ / 32), dim3(256), 0, stream>>>(query, pimg_ws, bs, ba, off_ws, attn_ws);
    k_vgemm <<<dim3(M_TOT / 64), dim3(256), 0, stream>>>(value, vimg_ws, bv, v_ws);
    k_sample<<<dim3(MQ_ / 2), dim3(256), 0, stream>>>(refp, off_ws, attn_ws, v_ws, mid_ws);
    k_ogemm <<<dim3(MQ_ / 32), dim3(256), 0, stream>>>(mid_ws, oimg_ws, bo, query, out);
}

// Round 11
// 95.957 us; speedup vs baseline: 2.2390x; 1.0655x over previous
//
#include <hip/hip_runtime.h>
#include <hip/hip_bf16.h>

// Deformable attention (Deformable-DETR) on MI355X.
// Static problem: B=8, NQ=900, E=256, H=8, L=4, P=4, dh=32, NV=19560
// levels (h,w): (92,160) (46,80) (23,40) (12,20); starts 0,14720,18400,19320

#define B_   8
#define NQ_  900
#define E_   256
#define H_   8
#define NV_  19560
#define M_TOT (B_ * NV_)   // 156480 = 64 * 2445 exactly
#define MQ_  (B_ * NQ_)    // 7200 = 32 * 225 exactly
#define NVB  2445          // vgemm blocks
#define NPB  225           // params blocks

typedef __attribute__((ext_vector_type(8)))  __bf16 bf16x8;
typedef __attribute__((ext_vector_type(4)))  float  f32x4;
typedef __attribute__((ext_vector_type(16))) float  f32x16;

__device__ __forceinline__ unsigned short f2bf(float x) {   // cold paths only
    unsigned int u = __builtin_bit_cast(unsigned int, x);
    u += 0x7FFFu + ((u >> 16) & 1u);          // RNE to bf16
    return (unsigned short)(u >> 16);
}

// hot-path conversion: v_cvt_pk_bf16_f32 via HIP intrinsic (1 op / 2 floats)
__device__ __forceinline__ unsigned int pack2bf(float a, float b) {
    union { __hip_bfloat162 h; unsigned int u; } r;
    r.h = __float22bfloat162_rn(make_float2(a, b));
    return r.u;
}

__device__ __forceinline__ bf16x8 cvt8(f32x4 lo, f32x4 hi) {
    union { bf16x8 v; unsigned int u[4]; } r;
    r.u[0] = pack2bf(lo.x, lo.y);
    r.u[1] = pack2bf(lo.z, lo.w);
    r.u[2] = pack2bf(hi.x, hi.y);
    r.u[3] = pack2bf(hi.z, hi.w);
    return r.v;
}

__device__ __forceinline__ unsigned short bf1(float x) {
    union { __hip_bfloat16 h; unsigned short u; } r;
    r.h = __float2bfloat16(x);
    return r.u;
}

#define GLL16(src, dst) \
    __builtin_amdgcn_global_load_lds( \
        (const __attribute__((address_space(1))) unsigned int*)(src), \
        (__attribute__((address_space(3))) unsigned int*)(dst), 16, 0, 0)

// ---------------------------------------------------------------- K0: prep
// Weight images in MFMA-B layout: img[(s*NCOL + col)*8 + j] = bf16(W[8s+j][col])
__global__ __launch_bounds__(256) void k_prep(
    const float* __restrict__ Wv, const float* __restrict__ Wo,
    const float* __restrict__ Ws, const float* __restrict__ Wa,
    unsigned short* __restrict__ vimg, unsigned short* __restrict__ oimg,
    unsigned short* __restrict__ pimg)
{
    const int i = blockIdx.x * 256 + threadIdx.x;   // 0..229375
    if (i < 131072) {
        const int e = i & 65535;
        const int j = e & 7, col = (e >> 3) & 255, h = (e >> 11) & 1, kf = e >> 12;
        const int k = kf * 16 + h * 8 + j;
        const float w = (i < 65536) ? Wv[k * 256 + col] : Wo[k * 256 + col];
        ((i < 65536) ? vimg : oimg)[e] = f2bf(w);
    } else {
        const int e = i - 131072;                   // 0..98303
        const int j = e & 7;
        const int q = e >> 3;                       // 0..12287
        const int col = q % 384, s = q / 384;
        const int h = s & 1, kf = s >> 1;
        const int k = kf * 16 + h * 8 + j;
        pimg[e] = f2bf(col < 256 ? Ws[k * 256 + col] : Wa[k * 128 + (col - 256)]);
    }
}

// ---------------------------------------------------------------- vgemm helpers
__device__ __forceinline__ void vg_stage(
    const float* __restrict__ value, const unsigned short* __restrict__ vimg,
    unsigned short* sA, unsigned short* sB, int row0, int ks, int t)
{
#pragma unroll
    for (int i = 0; i < 2; ++i) {               // A: 64 rows x 32 K fp32 (8 KB)
        const int u = i * 256 + t;              // 16B unit index
        const int row = u >> 3, qs = u & 7;
        const float* src = value + (long)(row0 + row) * 256 + ks * 32
                           + ((qs ^ (row & 7)) << 2);
        GLL16(src, sA + u * 8);
    }
#pragma unroll
    for (int i = 0; i < 4; ++i) {               // B: 256 cols x 32 K bf16 (16 KB)
        const int u = i * 256 + t;
        GLL16(vimg + (ks * 1024 + u) * 8, sB + u * 8);
    }
}

__device__ __forceinline__ void vg_compute(
    const unsigned short* sA, const unsigned short* sB,
    int lr, int hh, int w, f32x16 acc[2][2])
{
#pragma unroll
    for (int kk = 0; kk < 2; ++kk) {
        bf16x8 a8[2], b8[2];
#pragma unroll
        for (int m = 0; m < 2; ++m) {
            const int row = m * 32 + lr;
            const int q0 = kk * 4 + hh * 2;
            const f32x4 lo = *(const f32x4*)(sA + (row * 8 + ((q0    ) ^ (row & 7))) * 8);
            const f32x4 hi = *(const f32x4*)(sA + (row * 8 + ((q0 + 1) ^ (row & 7))) * 8);
            a8[m] = cvt8(lo, hi);
        }
#pragma unroll
        for (int n = 0; n < 2; ++n)
            b8[n] = *(const bf16x8*)(sB + ((kk * 2 + hh) * 256 + w * 64 + n * 32 + lr) * 8);
        __builtin_amdgcn_s_setprio(1);
#pragma unroll
        for (int m = 0; m < 2; ++m)
#pragma unroll
            for (int n = 0; n < 2; ++n)
                acc[m][n] = __builtin_amdgcn_mfma_f32_32x32x16_bf16(
                    a8[m], b8[n], acc[m][n], 0, 0, 0);
        __builtin_amdgcn_s_setprio(0);
    }
}

// ---------------------------------------------------------------- K1: vgemm + params (merged)
// blocks [0, NVB): v = value @ Wv + bv  (2-buffer counted-vmcnt pipeline)
// blocks [NVB, NVB+NPB): [off|logits] = query @ [Ws|Wa], softmax fused.
// Both paths use the same 48 KB LDS -> params blocks hide under vgemm.
__global__ __launch_bounds__(256) void k_vparams(
    const float* __restrict__ value, const unsigned short* __restrict__ vimg,
    const float* __restrict__ bv, unsigned short* __restrict__ v_out,
    const float* __restrict__ query, const unsigned short* __restrict__ pimg,
    const float* __restrict__ bs, const float* __restrict__ ba,
    float* __restrict__ off_out, float* __restrict__ attn_out)
{
    __shared__ __attribute__((aligned(16))) unsigned short sm[24576];  // 48 KB
    const int t = threadIdx.x, w = t >> 6, l = t & 63;
    const int lr = l & 31, hh = l >> 5;

    if (blockIdx.x < NVB) {
        // ================= vgemm path =================
        unsigned short* const sA_ = sm;           // 2 x 4096 ushorts (8 KB each)
        unsigned short* const sB_ = sm + 8192;    // 2 x 8192 ushorts (16 KB each)
#define SA_(p) (sA_ + (p) * 4096)
#define SB_(p) (sB_ + (p) * 8192)
        const int row0 = blockIdx.x * 64;

        f32x16 acc[2][2];
#pragma unroll
        for (int m = 0; m < 2; ++m)
#pragma unroll
            for (int n = 0; n < 2; ++n) acc[m][n] = (f32x16)(0.f);

        vg_stage(value, vimg, SA_(0), SB_(0), row0, 0, t);
        vg_stage(value, vimg, SA_(1), SB_(1), row0, 1, t);

#pragma unroll
        for (int ks = 0; ks < 8; ++ks) {
            if (ks < 7) asm volatile("s_waitcnt vmcnt(6)" ::: "memory");
            else        asm volatile("s_waitcnt vmcnt(0)" ::: "memory");
            __builtin_amdgcn_sched_barrier(0);
            __builtin_amdgcn_s_barrier();
            vg_compute(SA_(ks & 1), SB_(ks & 1), lr, hh, w, acc);
            __builtin_amdgcn_s_barrier();
            __builtin_amdgcn_sched_barrier(0);
            if (ks < 6)
                vg_stage(value, vimg, SA_(ks & 1), SB_(ks & 1), row0, ks + 2, t);
        }

#pragma unroll
        for (int n = 0; n < 2; ++n) {
            const int col = w * 64 + n * 32 + lr;
            const float bb = bv[col];
#pragma unroll
            for (int m = 0; m < 2; ++m)
#pragma unroll
                for (int r = 0; r < 16; ++r) {
                    const int row = row0 + m * 32 + (r & 3) + 8 * (r >> 2) + 4 * hh;
                    v_out[(long)row * 256 + col] = bf1(acc[m][n][r] + bb);
                }
        }
    } else {
        // ================= params path =================
        const int row0 = (blockIdx.x - NVB) * 32;
        const float* arow = query + (long)(row0 + lr) * 256;

        f32x16 acc[3];
#pragma unroll
        for (int n = 0; n < 3; ++n) acc[n] = (f32x16)(0.f);

        f32x4 al[2], ah[2];
        al[0] = *(const f32x4*)(arow + 0 * 16 + hh * 8);
        ah[0] = *(const f32x4*)(arow + 0 * 16 + hh * 8 + 4);
        al[1] = *(const f32x4*)(arow + 1 * 16 + hh * 8);
        ah[1] = *(const f32x4*)(arow + 1 * 16 + hh * 8 + 4);

#pragma unroll
        for (int p = 0; p < 4; ++p) {         // 4 phases x 48 KB of pimg
            if (p > 0) __syncthreads();       // previous phase's LDS reads done
#pragma unroll
            for (int i = 0; i < 12; ++i)
                GLL16(pimg + p * 24576 + (i * 256 + t) * 8, sm + (i * 256 + t) * 8);
            __syncthreads();                  // loads landed
#pragma unroll
            for (int kfp = 0; kfp < 4; ++kfp) {
                const int g = p * 4 + kfp;
                const int s = g & 1;
                const bf16x8 a8 = cvt8(al[s], ah[s]);
                if (g + 2 < 16) {
                    al[s] = *(const f32x4*)(arow + (g + 2) * 16 + hh * 8);
                    ah[s] = *(const f32x4*)(arow + (g + 2) * 16 + hh * 8 + 4);
                }
#pragma unroll
                for (int n = 0; n < 3; ++n) {
                    const bf16x8 b8 = *(const bf16x8*)
                        (sm + (((kfp * 2 + hh) * 384) + w * 96 + n * 32 + lr) * 8);
                    acc[n] = __builtin_amdgcn_mfma_f32_32x32x16_bf16(a8, b8, acc[n], 0, 0, 0);
                }
            }
        }

        __syncthreads();                      // all MFMA reads of sm done
        float* slog = (float*)sm;             // reuse: [32 rows][128 attn cols]
#pragma unroll
        for (int n = 0; n < 3; ++n) {
            const int gcol = w * 96 + n * 32 + lr;
#pragma unroll
            for (int r = 0; r < 16; ++r) {
                const int rl = (r & 3) + 8 * (r >> 2) + 4 * hh;
                if (gcol < 256)
                    off_out[(long)(row0 + rl) * 256 + gcol] = acc[n][r] + bs[gcol];
                else
                    slog[rl * 128 + (gcol - 256)] = acc[n][r] + ba[gcol - 256];
            }
        }
        __syncthreads();
        {
            const int row = t >> 3, h = t & 7;
            const float* pl = slog + row * 128 + h * 16;
            float m = pl[0];
#pragma unroll
            for (int j = 1; j < 16; ++j) m = fmaxf(m, pl[j]);
            float e[16]; float ssum = 0.f;
#pragma unroll
            for (int j = 0; j < 16; ++j) { e[j] = expf(pl[j] - m); ssum += e[j]; }
            const float inv = 1.0f / ssum;
            float* po = attn_out + (long)(row0 + row) * 128 + h * 16;
#pragma unroll
            for (int j = 0; j < 16; ++j) po[j] = e[j] * inv;
        }
    }
}

// ---------------------------------------------------------------- K3: sample
// Two-phase table-driven gather; XCD-bucketed grid: block i -> image i&7
// (round-robin wg->XCD dispatch puts each image's gathers on ONE XCD's L2).
__global__ __launch_bounds__(256) void k_sample(
    const float* __restrict__ refp, const float* __restrict__ off,
    const float* __restrict__ attn, const unsigned short* __restrict__ v,
    unsigned short* __restrict__ out_mid)
{
    __shared__ int2 spt[1024];   // [point(256)][corner(4)] = {elem-offset, weight bits}
    const int t = threadIdx.x;
    const int img = blockIdx.x & 7, pr = blockIdx.x >> 3;   // 8 x 450
    const int bq0 = img * NQ_ + pr * 2;

    constexpr int HS[4] = {92, 46, 23, 12};
    constexpr int WS_[4] = {160, 80, 40, 20};
    constexpr int ST[4] = {0, 14720, 18400, 19320};

    // ---- phase 1: one point per thread ----
    {
        const int qi = t >> 7, c = t & 127;
        const int h = c >> 4, lv = (c >> 2) & 3, p = c & 3;
        const int bq = bq0 + qi;
        const int Hl = HS[lv], Wl = WS_[lv], st = ST[lv];
        const float rx = refp[bq * 8 + lv * 2 + 0];
        const float ry = refp[bq * 8 + lv * 2 + 1];
        const float ox = off[(long)bq * 256 + h * 32 + lv * 8 + p * 2 + 0];
        const float oy = off[(long)bq * 256 + h * 32 + lv * 8 + p * 2 + 1];
        const float aw = attn[(long)bq * 128 + h * 16 + lv * 4 + p];
        const float x = fmaf(rx, (float)Wl, ox) - 0.5f;
        const float y = fmaf(ry, (float)Hl, oy) - 0.5f;
        const float x0f = floorf(x), y0f = floorf(y);
        const int x0 = (int)x0f, y0 = (int)y0f;
        const float wx1 = x - x0f, wx0 = 1.f - wx1;
        const float wy1 = y - y0f, wy0 = 1.f - wy1;
#pragma unroll
        for (int cnr = 0; cnr < 4; ++cnr) {
            const int dx = cnr & 1, dy = cnr >> 1;
            const int xi = x0 + dx, yi = y0 + dy;
            const bool valid = (xi >= 0) && (xi < Wl) && (yi >= 0) && (yi < Hl);
            const int xc = min(max(xi, 0), Wl - 1);
            const int yc = min(max(yi, 0), Hl - 1);
            const float wgt = (dx ? wx1 : wx0) * (dy ? wy1 : wy0) * aw;
            spt[t * 4 + cnr] = make_int2((st + yc * Wl + xc) * 128,
                                         __builtin_bit_cast(int, valid ? wgt : 0.f));
        }
    }
    __syncthreads();

    // ---- phase 2: table-driven gather ----
    const int qi = t >> 7, tt = t & 127;
    const int h = tt >> 4, dp = tt & 15;
    const int bq = bq0 + qi;
    const unsigned int* vb = (const unsigned int*)(v + (long)img * NV_ * 256)
                             + h * 16 + dp;
    const int2* tbl = spt + (qi * 128 + h * 16) * 4;
    float acc0 = 0.f, acc1 = 0.f;
#pragma unroll
    for (int j = 0; j < 16; ++j) {
#pragma unroll
        for (int cnr = 0; cnr < 4; ++cnr) {
            const int2 ow = tbl[j * 4 + cnr];
            const unsigned int u = vb[ow.x];
            const float wgt = __builtin_bit_cast(float, ow.y);
            acc0 = fmaf(__builtin_bit_cast(float, u << 16), wgt, acc0);
            acc1 = fmaf(__builtin_bit_cast(float, u & 0xFFFF0000u), wgt, acc1);
        }
    }
    *(unsigned int*)(out_mid + (long)bq * 256 + h * 32 + dp * 2) = pack2bf(acc0, acc1);
}

// ---------------------------------------------------------------- K4: out GEMM (MFMA)
// out = mid(bf16) @ Wo + bo + query. BM=32, persistent-B 64KB, 2 phases.
__global__ __launch_bounds__(256) void k_ogemm(
    const unsigned short* __restrict__ mid, const unsigned short* __restrict__ oimg,
    const float* __restrict__ bo, const float* __restrict__ query,
    float* __restrict__ out)
{
    __shared__ unsigned short sB[32768];   // 64 KB
    const int t = threadIdx.x, w = t >> 6, l = t & 63;
    const int lr = l & 31, hh = l >> 5;
    const int row0 = blockIdx.x * 32;
    const unsigned short* arow = mid + (long)(row0 + lr) * 256;

    f32x16 acc[2];
#pragma unroll
    for (int n = 0; n < 2; ++n) acc[n] = (f32x16)(0.f);

    bf16x8 areg[2];
    areg[0] = *(const bf16x8*)(arow + 0 * 16 + hh * 8);
    areg[1] = *(const bf16x8*)(arow + 1 * 16 + hh * 8);

#pragma unroll
    for (int i = 0; i < 16; ++i)
        GLL16(oimg + (i * 256 + t) * 8, sB + (i * 256 + t) * 8);
    __syncthreads();

#pragma unroll
    for (int ph = 0; ph < 2; ++ph) {
        if (ph == 1) {
            __syncthreads();
#pragma unroll
            for (int i = 0; i < 16; ++i)
                GLL16(oimg + 32768 + (i * 256 + t) * 8, sB + (i * 256 + t) * 8);
            __syncthreads();
        }
#pragma unroll
        for (int kfp = 0; kfp < 8; ++kfp) {
            const int g = ph * 8 + kfp;
            const int s = g & 1;
            const bf16x8 a8 = areg[s];
            if (g + 2 < 16)
                areg[s] = *(const bf16x8*)(arow + (g + 2) * 16 + hh * 8);
#pragma unroll
            for (int n = 0; n < 2; ++n) {
                const bf16x8 b8 = *(const bf16x8*)
                    (sB + (((kfp * 2 + hh) * 256) + w * 64 + n * 32 + lr) * 8);
                acc[n] = __builtin_amdgcn_mfma_f32_32x32x16_bf16(a8, b8, acc[n], 0, 0, 0);
            }
        }
    }

#pragma unroll
    for (int n = 0; n < 2; ++n) {
        const int col = w * 64 + n * 32 + lr;
        const float bb = bo[col];
#pragma unroll
        for (int r = 0; r < 16; ++r) {
            const int row = row0 + (r & 3) + 8 * (r >> 2) + 4 * hh;
            out[(long)row * 256 + col] = acc[n][r] + bb + query[(long)row * 256 + col];
        }
    }
}

// ---------------------------------------------------------------- launch
extern "C" void kernel_launch(void* const* d_in, const int* in_sizes, int n_in,
                              void* d_out, int out_size, void* d_ws, size_t ws_size,
                              hipStream_t stream)
{
    const float* query = (const float*)d_in[0];
    const float* value = (const float*)d_in[1];
    const float* refp  = (const float*)d_in[2];
    const float* Wv    = (const float*)d_in[3];
    const float* bv    = (const float*)d_in[4];
    const float* Ws    = (const float*)d_in[5];
    const float* bs    = (const float*)d_in[6];
    const float* Wa    = (const float*)d_in[7];
    const float* ba    = (const float*)d_in[8];
    const float* Wo    = (const float*)d_in[9];
    const float* bo    = (const float*)d_in[10];
    float* out = (float*)d_out;

    char* ws = (char*)d_ws;
    unsigned short* v_ws  = (unsigned short*)ws;                    // 80,117,760 B
    float* off_ws  = (float*)(ws + 80117760);                       //  7,372,800 B
    float* attn_ws = (float*)(ws + 87490560);                       //  3,686,400 B
    unsigned short* mid_ws  = (unsigned short*)(ws + 91176960);     //  3,686,400 B
    unsigned short* vimg_ws = (unsigned short*)(ws + 94863360);     //    131,072 B
    unsigned short* pimg_ws = (unsigned short*)(ws + 94994432);     //    196,608 B
    unsigned short* oimg_ws = (unsigned short*)(ws + 95191040);     //    131,072 B

    k_prep   <<<dim3(896), dim3(256), 0, stream>>>(Wv, Wo, Ws, Wa, vimg_ws, oimg_ws, pimg_ws);
    k_vparams<<<dim3(NVB + NPB), dim3(256), 0, stream>>>(value, vimg_ws, bv, v_ws,
                                                         query, pimg_ws, bs, ba,
                                                         off_ws, attn_ws);
    k_sample <<<dim3(MQ_ / 2), dim3(256), 0, stream>>>(refp, off_ws, attn_ws, v_ws, mid_ws);
    k_ogemm  <<<dim3(MQ_ / 32), dim3(256), 0, stream>>>(mid_ws, oimg_ws, bo, query, out);
}